// Round 11
// baseline (418.864 us; speedup 1.0000x reference)
//
#include <hip/hip_runtime.h>
#include <stdint.h>

#define Bq 32
#define Nq 512
#define Hq 128
#define NHq 8
#define HDq 16
#define Mq (Bq * Nq)   // 16384

typedef unsigned short u16;
typedef __attribute__((ext_vector_type(8))) short short8;
typedef __attribute__((ext_vector_type(8))) _Float16 half8;
typedef __attribute__((ext_vector_type(2))) __fp16 fp16x2;
typedef __attribute__((ext_vector_type(4))) float f32x4;

#define LOG2E 1.4426950408889634f
#define QSCALE 0.36067376022224085f   // 0.25 * log2(e)

// ---------- dtype-flex helpers (flag: 1 = inputs are bf16, 0 = f32) ----------
__device__ __forceinline__ float bf2f(u16 v) {
    return __uint_as_float(((unsigned int)v) << 16);
}
__device__ __forceinline__ float ldin(const void* p, long idx, int bf) {
    if (bf) return bf2f(((const u16*)p)[idx]);
    return ((const float*)p)[idx];
}
__device__ __forceinline__ u16 f2bf(float v) {   // RNE
    unsigned int u = __float_as_uint(v);
    return (u16)((u + 0x7FFFu + ((u >> 16) & 1u)) >> 16);
}
__device__ __forceinline__ u16 f2h(float v) {    // f32 -> f16 bits (RNE)
    _Float16 h = (_Float16)v;
    return *(u16*)&h;
}
__device__ __forceinline__ unsigned pk2h(float a, float b) {  // packed f16 pair bits
    fp16x2 c = __builtin_amdgcn_cvt_pkrtz(a, b);
    return *(unsigned*)&c;
}

// ---------- merged prep: dtype detect + converts + mask bits + kprep ----------
__global__ void prep_kernel(const void* xraw, const void* de, const void* ab,
                            const void* mraw, int* flag, float* deo, float* abo,
                            unsigned* mbits, int n,
                            u16* __restrict__ kidxg, int* __restrict__ nkt,
                            unsigned* __restrict__ tmask) {
    __shared__ int cnt, orA, orB, orC, orD;
    __shared__ unsigned smb[512];
    int tid = threadIdx.x;
    if (tid == 0) { cnt = 0; orA = 0; orB = 0; orC = 0; orD = 0; }
    __syncthreads();
    const u16* u = (const u16*)xraw;
    int good = 0;
    for (int i = tid; i < 1024; i += 256) {
        u16 v = u[i];
        int e = (v >> 7) & 0xFF;
        if (v == 0 || (e >= 90 && e <= 141)) good++;
    }
    atomicAdd(&cnt, good);
    const uint4* p4 = (const uint4*)mraw;
    unsigned a = 0, b = 0, c = 0, d = 0;
    for (int i = tid; i < n / 16; i += 256) {
        uint4 w = p4[i];
        unsigned all = w.x | w.y | w.z | w.w;
        a |= all & 0xFEFEFEFEu;
        b |= all & 0x0000FF00u;
        c |= all & 0xFFFFFF00u;
        d |= w.y | w.w;
    }
    if (a) atomicOr(&orA, 1);
    if (b) atomicOr(&orB, 1);
    if (c) atomicOr(&orC, 1);
    if (d) atomicOr(&orD, 1);
    __syncthreads();
    int bf = (cnt >= 900);
    if (tid == 0) *flag = bf;
    int mode;  // 0 bool8, 1 int32, 2 int64, 3 bf16, 4 f32
    if (orA) mode = orB ? 3 : 4;
    else if (orC) mode = 0;
    else mode = orD ? 1 : 2;
    for (int i = tid; i < 1200; i += 256) deo[i] = ldin(de, i, bf);
    if (tid < 24) abo[tid] = ldin(ab, tid, bf);
    const unsigned char* p = (const unsigned char*)mraw;
    for (int wI = tid; wI < n / 32; wI += 256) {
        unsigned word = 0;
        for (int j = 0; j < 32; ++j) {
            int i = wI * 32 + j;
            int v;
            switch (mode) {
                case 0: v = p[i]; break;
                case 1: v = ((const int*)p)[i]; break;
                case 2: v = (int)((const long long*)p)[i]; break;
                case 3: v = ((const u16*)p)[i] != 0; break;
                default: v = (((const float*)p)[i] != 0.0f); break;
            }
            if (v) word |= 1u << j;
        }
        mbits[wI] = word;
        smb[wI] = word;
    }
    __syncthreads();
    // --- kprep fold: 64-lane groups sweep batches ---
    int lane = tid & 63;
    for (int bb = tid >> 6; bb < 32; bb += 4) {
        int pos_base = 0;
        for (int w = 0; w < 8; ++w) {
            unsigned lo = smb[bb * 16 + 2 * w], hi = smb[bb * 16 + 2 * w + 1];
            unsigned long long word = ((unsigned long long)hi << 32) | lo;
            unsigned long long un = ~word;   // 1 = unmasked
            int bit = (int)((un >> lane) & 1ull);
            unsigned long long before = un & ((1ull << lane) - 1ull);
            int pos = pos_base + __popcll(before);
            if (bit) kidxg[bb * 512 + pos] = (u16)(w * 64 + lane);
            pos_base += __popcll(un);
        }
        int nk = pos_base;
        int nkp = (nk + 31) & ~31;
        if (nkp == 0) nkp = 32;
        int nt = nkp >> 5;
        for (int j = nk + lane; j < nkp; j += 64) kidxg[bb * 512 + j] = 0;
        if (lane == 0) {
            nkt[bb] = nt;
            for (int t = 0; t < 16; ++t) tmask[bb * 16 + t] = 0;
            int rem = nk & 31;
            if (rem) tmask[bb * 16 + nt - 1] = 0xFFFFFFFFu << rem;
            if (nk == 0) tmask[bb * 16] = 0xFFFFFFFFu;
        }
    }
}

// ---------- setup2: binsc + init + wtrans fused (range-switched grid) ------
// [0,2048): binsc. [2048,3072): init copy. [3072,3840): wtrans.
__global__ __launch_bounds__(256) void setup2_kernel(
    const void* __restrict__ dist, const u16* __restrict__ kidxg,
    const int* __restrict__ nktp, unsigned char* __restrict__ binsc,
    const void* x, float* __restrict__ h,
    const void* Wqr, const void* Wkr, const void* Wvr, const void* Wor,
    const void* Wf1r, const void* Wf2r,
    u16* qkvT, u16* oT, u16* f1T, u16* f2T, const int* flagp) {
    __shared__ u16 kl[512];
    __shared__ int ntS;
    __shared__ u16 Ts[32][33];
    int id = blockIdx.x;
    int tid = threadIdx.x;
    int bf = *flagp;
    if (id < 2048) {
        int b = id >> 6;
        int q0 = (id & 63) * 8;
        if (tid == 0) ntS = nktp[b];
        kl[tid] = kidxg[b * 512 + tid];
        kl[tid + 256] = kidxg[b * 512 + tid + 256];
        __syncthreads();
        int nkp = ntS * 32;
        for (int rq = 0; rq < 8; ++rq) {
            int q = q0 + rq;
            long rowoff = ((long)b * 512 + q) * 512;
            for (int j = tid; j < nkp; j += 256) {
                float d = ldin(dist, rowoff + kl[j], bf);
                int v = (int)(d * 10.0f);
                v = v < 0 ? 0 : (v > 49 ? 49 : v);
                binsc[((size_t)b * 512 + q) * 512 + j] = (unsigned char)(v << 2);
            }
        }
    } else if (id < 3072) {
        int i = (id - 2048) * 256 + tid;
        long base = (long)i * 8;
        if (bf) {
            uint4 w = ((const uint4*)x)[i];
            const u16* ws = (const u16*)&w;
            float o[8];
#pragma unroll
            for (int k = 0; k < 8; ++k) o[k] = bf2f(ws[k]);
            *(float4*)&h[base] = *(float4*)&o[0];
            *(float4*)&h[base + 4] = *(float4*)&o[4];
        } else {
            float4 a = ((const float4*)x)[2 * i];
            float4 b2v = ((const float4*)x)[2 * i + 1];
            *(float4*)&h[base] = a;
            *(float4*)&h[base + 4] = b2v;
        }
    } else {
        int bid = id - 3072;
        int l = bid >> 8, r = bid & 255;
        const void* src; u16* dst; long soff, doff; int Kd, Nd, t;
        if (r < 64) {
            int mat = r >> 4; t = r & 15; Kd = 128; Nd = 128;
            soff = (long)l * 16384;
            if (mat == 0)      { src = Wqr; dst = qkvT; doff = (long)l * 49152; }
            else if (mat == 1) { src = Wkr; dst = qkvT; doff = (long)l * 49152 + 16384; }
            else if (mat == 2) { src = Wvr; dst = qkvT; doff = (long)l * 49152 + 32768; }
            else               { src = Wor; dst = oT;   doff = (long)l * 16384; }
        } else if (r < 192) {
            t = r - 64; Kd = 128; Nd = 1024;
            src = Wf1r; soff = (long)l * 131072; dst = f1T; doff = (long)l * 131072;
        } else {
            t = r - 192; Kd = 512; Nd = 128;
            src = Wf2r; soff = (long)l * 65536; dst = f2T; doff = (long)l * 65536;
        }
        int ntile = Nd >> 5;
        int tk = t / ntile, tn = t % ntile;
        int rr = tid >> 3, cc0 = (tid & 7) * 4;
#pragma unroll
        for (int i = 0; i < 4; ++i) {
            long idx = soff + (long)(tk * 32 + rr) * Nd + tn * 32 + cc0 + i;
            Ts[rr][cc0 + i] = f2bf(ldin(src, idx, bf));
        }
        __syncthreads();
#pragma unroll
        for (int i = 0; i < 4; ++i) {
            long idx = doff + (long)(tn * 32 + rr) * Kd + tk * 32 + cc0 + i;
            dst[idx] = Ts[cc0 + i][rr];
        }
    }
}

// ===== QKV (layer 0 only): LN once, Q/K/V looped, B streamed from L2 =====
__global__ __launch_bounds__(256, 4) void qkv_mfma_kernel(
    const float* __restrict__ h, const u16* __restrict__ qkvT_l,
    const void* bqr, const void* bkr, const void* bvr, long bOff,
    const void* g1raw, const void* b1raw, long lnOff,
    u16* __restrict__ Qo, u16* __restrict__ Ko, u16* __restrict__ Vo,
    const int* flagp) {
    __shared__ __align__(16) u16 As[32][136];
    int tid = threadIdx.x;
    int m0 = blockIdx.x * 32;
    int bf = *flagp;
    {
        int row = tid >> 3, c0 = (tid & 7) * 16;
        const float* hp = h + (size_t)(m0 + row) * 128 + c0;
        float4 f0 = *(const float4*)(hp);
        float4 f1 = *(const float4*)(hp + 4);
        float4 f2 = *(const float4*)(hp + 8);
        float4 f3 = *(const float4*)(hp + 12);
        float vv[16] = {f0.x, f0.y, f0.z, f0.w, f1.x, f1.y, f1.z, f1.w,
                        f2.x, f2.y, f2.z, f2.w, f3.x, f3.y, f3.z, f3.w};
        float s = 0.f, s2 = 0.f;
#pragma unroll
        for (int k = 0; k < 16; ++k) { s += vv[k]; s2 += vv[k] * vv[k]; }
#pragma unroll
        for (int o = 1; o < 8; o <<= 1) {
            s += __shfl_xor(s, o);
            s2 += __shfl_xor(s2, o);
        }
        float mu = s * (1.0f / 128.0f);
        float var = fmaxf(s2 * (1.0f / 128.0f) - mu * mu, 0.0f);
        float rstd = rsqrtf(var + 1e-5f);
        u16 tmp[16];
#pragma unroll
        for (int k = 0; k < 16; ++k) {
            float g = ldin(g1raw, lnOff + c0 + k, bf);
            float b = ldin(b1raw, lnOff + c0 + k, bf);
            tmp[k] = f2bf((vv[k] - mu) * rstd * g + b);
        }
        *(uint4*)&As[row][c0]     = *(uint4*)&tmp[0];
        *(uint4*)&As[row][c0 + 8] = *(uint4*)&tmp[8];
    }
    __syncthreads();
    int wave = tid >> 6, lane = tid & 63;
    int q = lane >> 4, ln = lane & 15;
    int nb = wave * 32;
    f32x4 zero = {0.f, 0.f, 0.f, 0.f};
#pragma unroll
    for (int mat = 0; mat < 3; ++mat) {
        const u16* WT = qkvT_l + (size_t)mat * 16384;
        const void* braw = mat == 0 ? bqr : (mat == 1 ? bkr : bvr);
        u16* C = mat == 0 ? Qo : (mat == 1 ? Ko : Vo);
        float scale = mat == 0 ? QSCALE : 1.0f;
        short8 bfr[2][4];
#pragma unroll
        for (int t = 0; t < 2; ++t)
#pragma unroll
            for (int k4 = 0; k4 < 4; ++k4)
                bfr[t][k4] = *(const short8*)(WT + (size_t)(nb + t * 16 + ln) * 128
                                              + k4 * 32 + q * 8);
        f32x4 acc[2][2];
#pragma unroll
        for (int i = 0; i < 2; ++i)
#pragma unroll
            for (int j = 0; j < 2; ++j) acc[i][j] = zero;
#pragma unroll
        for (int k4 = 0; k4 < 4; ++k4) {
            short8 af0 = *(const short8*)&As[ln][k4 * 32 + q * 8];
            short8 af1 = *(const short8*)&As[16 + ln][k4 * 32 + q * 8];
#pragma unroll
            for (int t = 0; t < 2; ++t) {
                acc[0][t] = __builtin_amdgcn_mfma_f32_16x16x32_bf16(
                    af0, bfr[t][k4], acc[0][t], 0, 0, 0);
                acc[1][t] = __builtin_amdgcn_mfma_f32_16x16x32_bf16(
                    af1, bfr[t][k4], acc[1][t], 0, 0, 0);
            }
        }
#pragma unroll
        for (int t = 0; t < 2; ++t) {
            int n = nb + t * 16 + ln;
            float bias = ldin(braw, bOff + n, bf);
#pragma unroll
            for (int mi = 0; mi < 2; ++mi)
#pragma unroll
                for (int r = 0; r < 4; ++r) {
                    int m = m0 + mi * 16 + q * 4 + r;
                    C[(size_t)m * 128 + n] = f2h((acc[mi][t][r] + bias) * scale);
                }
        }
    }
}

// ===== fused FFN v5: 16-row tiles, grid 1024, 21.5 KB LDS, 4 blocks/CU =====
// (16 waves/CU = 50% occupancy cap, 2x the 32-row version). Same structure:
// o-proj+resid+LN2+GLU-ff1+ff2+resid + optional next-layer LN1+QKV.
// B streamed from L2, transient registers only, 6 barriers.
__global__ __launch_bounds__(256, 4) void ffglu_kernel(
    const u16* __restrict__ att, const u16* __restrict__ oT_l,
    const void* __restrict__ bo, long boOff, float* __restrict__ h,
    const void* g2, const void* b2, long ln2Off,
    const u16* __restrict__ f1T_l, const void* __restrict__ bf1r, long bf1Off,
    const u16* __restrict__ f2T_l, const void* __restrict__ bf2r, long bf2Off,
    void* __restrict__ outp, const int* flagp,
    const u16* __restrict__ qkvTn,    // next layer qkvT (or nullptr)
    const void* bqr, const void* bkr, const void* bvr, long bOffN,
    const void* g1, const void* b1, long ln1OffN,
    u16* __restrict__ Qo, u16* __restrict__ Ko, u16* __restrict__ Vo) {
    __shared__ __align__(16) u16 As[16][136];   // att stage / hn2 / hn1-next
    __shared__ __align__(16) u16 vg[16][520];   // GLU output (never to HBM)
    __shared__ float stats[16][4][2];
    int tid = threadIdx.x;
    int m0 = blockIdx.x * 16;
    int wave = tid >> 6, lane = tid & 63;
    int q = lane >> 4, ln = lane & 15;
    int nb = wave * 32;
    int bf = *flagp;
    f32x4 zero = {0.f, 0.f, 0.f, 0.f};

    // ---- stage att [16][128]: 256 uint4, 1 per thread ----
    { int r = tid >> 4, c = (tid & 15) << 3;
      *(uint4*)&As[r][c] = *(const uint4*)(att + (size_t)(m0 + r) * 128 + c); }
    __syncthreads();                                   // B1
    // ---- o-proj: B streamed ----
    f32x4 acc[2] = {zero, zero};
    {
        short8 bfr[2][4];
#pragma unroll
        for (int t = 0; t < 2; ++t)
#pragma unroll
            for (int k4 = 0; k4 < 4; ++k4)
                bfr[t][k4] = *(const short8*)(oT_l + (size_t)(nb + t * 16 + ln) * 128
                                              + k4 * 32 + q * 8);
#pragma unroll
        for (int k4 = 0; k4 < 4; ++k4) {
            short8 af = *(const short8*)&As[ln][k4 * 32 + q * 8];
#pragma unroll
            for (int t = 0; t < 2; ++t)
                acc[t] = __builtin_amdgcn_mfma_f32_16x16x32_bf16(
                    af, bfr[t][k4], acc[t], 0, 0, 0);
        }
    }
    // ---- epilogue: +bias +resid(h) -> h1 regs; LN2 partial stats ----
    float h1[2][4];
    float srow[4] = {0.f, 0.f, 0.f, 0.f}, s2row[4] = {0.f, 0.f, 0.f, 0.f};
#pragma unroll
    for (int t = 0; t < 2; ++t) {
        int n = nb + t * 16 + ln;
        float bias = ldin(bo, boOff + n, bf);
#pragma unroll
        for (int r = 0; r < 4; ++r) {
            float v = acc[t][r] + bias +
                      h[(size_t)(m0 + q * 4 + r) * 128 + n];
            h1[t][r] = v;
            srow[r] += v; s2row[r] += v * v;
        }
    }
#pragma unroll
    for (int r = 0; r < 4; ++r)
#pragma unroll
        for (int o = 1; o < 16; o <<= 1) {
            srow[r] += __shfl_xor(srow[r], o);
            s2row[r] += __shfl_xor(s2row[r], o);
        }
    if (ln == 0) {
#pragma unroll
        for (int r = 0; r < 4; ++r) {
            stats[q * 4 + r][wave][0] = srow[r];
            stats[q * 4 + r][wave][1] = s2row[r];
        }
    }
    __syncthreads();                                   // B2
    // ---- LN2 -> hn2 (As overlay) ----
    float mu[4], rs[4];
#pragma unroll
    for (int r = 0; r < 4; ++r) {
        int row = q * 4 + r;
        float s = (stats[row][0][0] + stats[row][1][0]) +
                  (stats[row][2][0] + stats[row][3][0]);
        float s2 = (stats[row][0][1] + stats[row][1][1]) +
                   (stats[row][2][1] + stats[row][3][1]);
        mu[r] = s * (1.0f / 128.0f);
        float var = fmaxf(s2 * (1.0f / 128.0f) - mu[r] * mu[r], 0.0f);
        rs[r] = rsqrtf(var + 1e-5f);
    }
#pragma unroll
    for (int t = 0; t < 2; ++t) {
        int n = nb + t * 16 + ln;
        float g = ldin(g2, ln2Off + n, bf), bb = ldin(b2, ln2Off + n, bf);
#pragma unroll
        for (int r = 0; r < 4; ++r)
            As[q * 4 + r][n] = f2bf((h1[t][r] - mu[r]) * rs[r] * g + bb);
    }
    __syncthreads();                                   // B3
    // ---- ff1: 8 chunks of 64 GLU cols, no barriers ----
    int nb16 = wave * 16;
    for (int ch = 0; ch < 8; ++ch) {
        int arow = ch * 64 + nb16;
        short8 ba[4], bb8[4];
#pragma unroll
        for (int k4 = 0; k4 < 4; ++k4) {
            ba[k4]  = *(const short8*)(f1T_l + (size_t)(arow + ln) * 128
                                       + k4 * 32 + q * 8);
            bb8[k4] = *(const short8*)(f1T_l + (size_t)(512 + arow + ln) * 128
                                       + k4 * 32 + q * 8);
        }
        f32x4 aA = zero, aB = zero;
#pragma unroll
        for (int k4 = 0; k4 < 4; ++k4) {
            short8 af = *(const short8*)&As[ln][k4 * 32 + q * 8];
            aA = __builtin_amdgcn_mfma_f32_16x16x32_bf16(af, ba[k4], aA, 0, 0, 0);
            aB = __builtin_amdgcn_mfma_f32_16x16x32_bf16(af, bb8[k4], aB, 0, 0, 0);
        }
        int n = arow + ln;
        float bA = ldin(bf1r, bf1Off + n, bf);
        float bB = ldin(bf1r, bf1Off + 512 + n, bf);
#pragma unroll
        for (int r = 0; r < 4; ++r) {
            float ua = aA[r] + bA, ub = aB[r] + bB;
            vg[q * 4 + r][n] = f2bf(ua / (1.0f + __expf(-ub)));
        }
    }
    __syncthreads();                                   // B4
    // ---- ff2: K=512 in 4 chunks, B streamed ----
    f32x4 accF[2] = {zero, zero};
    for (int fc = 0; fc < 4; ++fc) {
        short8 bfr[2][4];
#pragma unroll
        for (int t = 0; t < 2; ++t)
#pragma unroll
            for (int k4 = 0; k4 < 4; ++k4)
                bfr[t][k4] = *(const short8*)(f2T_l + (size_t)(nb + t * 16 + ln) * 512
                                              + fc * 128 + k4 * 32 + q * 8);
#pragma unroll
        for (int k4 = 0; k4 < 4; ++k4) {
            short8 af = *(const short8*)&vg[ln][fc * 128 + k4 * 32 + q * 8];
#pragma unroll
            for (int t = 0; t < 2; ++t)
                accF[t] = __builtin_amdgcn_mfma_f32_16x16x32_bf16(
                    af, bfr[t][k4], accF[t], 0, 0, 0);
        }
    }
    // ---- epilogue: +bias +resid -> h (and h1 regs for next-layer LN1) ----
#pragma unroll
    for (int t = 0; t < 2; ++t) {
        int n = nb + t * 16 + ln;
        float bias = ldin(bf2r, bf2Off + n, bf);
#pragma unroll
        for (int r = 0; r < 4; ++r) {
            int m = m0 + q * 4 + r;
            float v = accF[t][r] + bias + h1[t][r];
            h[(size_t)m * 128 + n] = v;
            h1[t][r] = v;   // reuse for LN1-next
            if (outp) {
                if (bf) ((u16*)outp)[(size_t)m * 128 + n] = f2bf(v);
                else ((float*)outp)[(size_t)m * 128 + n] = v;
            }
        }
    }
    if (!qkvTn) return;
    // ---- LN1 (next layer) stats ----
#pragma unroll
    for (int r = 0; r < 4; ++r) { srow[r] = 0.f; s2row[r] = 0.f; }
#pragma unroll
    for (int t = 0; t < 2; ++t)
#pragma unroll
        for (int r = 0; r < 4; ++r) {
            float v = h1[t][r];
            srow[r] += v; s2row[r] += v * v;
        }
#pragma unroll
    for (int r = 0; r < 4; ++r)
#pragma unroll
        for (int o = 1; o < 16; o <<= 1) {
            srow[r] += __shfl_xor(srow[r], o);
            s2row[r] += __shfl_xor(s2row[r], o);
        }
    if (ln == 0) {
#pragma unroll
        for (int r = 0; r < 4; ++r) {
            stats[q * 4 + r][wave][0] = srow[r];
            stats[q * 4 + r][wave][1] = s2row[r];
        }
    }
    __syncthreads();                                   // B5
#pragma unroll
    for (int r = 0; r < 4; ++r) {
        int row = q * 4 + r;
        float s = (stats[row][0][0] + stats[row][1][0]) +
                  (stats[row][2][0] + stats[row][3][0]);
        float s2 = (stats[row][0][1] + stats[row][1][1]) +
                   (stats[row][2][1] + stats[row][3][1]);
        mu[r] = s * (1.0f / 128.0f);
        float var = fmaxf(s2 * (1.0f / 128.0f) - mu[r] * mu[r], 0.0f);
        rs[r] = rsqrtf(var + 1e-5f);
    }
#pragma unroll
    for (int t = 0; t < 2; ++t) {
        int n = nb + t * 16 + ln;
        float g = ldin(g1, ln1OffN + n, bf), bb = ldin(b1, ln1OffN + n, bf);
#pragma unroll
        for (int r = 0; r < 4; ++r)
            As[q * 4 + r][n] = f2bf((h1[t][r] - mu[r]) * rs[r] * g + bb);
    }
    __syncthreads();                                   // B6
    // ---- next-layer QKV: B streamed ----
#pragma unroll
    for (int mat = 0; mat < 3; ++mat) {
        const u16* WT = qkvTn + (size_t)mat * 16384;
        const void* braw = mat == 0 ? bqr : (mat == 1 ? bkr : bvr);
        u16* C = mat == 0 ? Qo : (mat == 1 ? Ko : Vo);
        float scale = mat == 0 ? QSCALE : 1.0f;
        short8 bfr[2][4];
#pragma unroll
        for (int t = 0; t < 2; ++t)
#pragma unroll
            for (int k4 = 0; k4 < 4; ++k4)
                bfr[t][k4] = *(const short8*)(WT + (size_t)(nb + t * 16 + ln) * 128
                                              + k4 * 32 + q * 8);
        f32x4 aq[2] = {zero, zero};
#pragma unroll
        for (int k4 = 0; k4 < 4; ++k4) {
            short8 af = *(const short8*)&As[ln][k4 * 32 + q * 8];
#pragma unroll
            for (int t = 0; t < 2; ++t)
                aq[t] = __builtin_amdgcn_mfma_f32_16x16x32_bf16(
                    af, bfr[t][k4], aq[t], 0, 0, 0);
        }
#pragma unroll
        for (int t = 0; t < 2; ++t) {
            int n = nb + t * 16 + ln;
            float bias = ldin(braw, bOffN + n, bf);
#pragma unroll
            for (int r = 0; r < 4; ++r) {
                int m = m0 + q * 4 + r;
                C[(size_t)m * 128 + n] = f2h((aq[t][r] + bias) * scale);
            }
        }
    }
}

// ========== attention v6: exp2-domain softmax (Q pre-scaled by log2e) =======
__global__ __launch_bounds__(256, 4) void attn_kernel(
    const u16* __restrict__ Qh, const u16* __restrict__ Kh,
    const u16* __restrict__ Vh, const unsigned char* __restrict__ binsc,
    const u16* __restrict__ kidxg, const int* __restrict__ nktp,
    const unsigned* __restrict__ tmaskp, const float* __restrict__ deL,
    const float* __restrict__ abL, u16* __restrict__ out) {
    // de-swizzle: heads of one (b,qq) share id%8 -> same XCD L2 for binsc
    int id = blockIdx.x;
    int c = id & 7, t5 = id >> 3;
    int nh = t5 & 7;
    int pair = ((t5 >> 3) << 3) | c;
    int b = pair >> 2, qq = pair & 3;

    __shared__ __align__(16) u16 KsF[8192];      // frag-major K, 16 KB
    __shared__ __align__(16) u16 VT[16 * 520];   // V^T rows 520 f16, 16.25 KB
    __shared__ __align__(16) u16 Pl[4 * 16 * 40];// per-wave P tile, 5 KB

    int tid = threadIdx.x;
    int nt = __builtin_amdgcn_readfirstlane(nktp[b]);
    int nkp = nt * 32;
    const u16* Kp = Kh + (size_t)(b * Nq) * Hq + nh * HDq;
    const u16* Vp = Vh + (size_t)(b * Nq) * Hq + nh * HDq;
    for (int r = tid; r < nkp; r += 256) {
        int row = kidxg[b * 512 + r];
        int kt = r >> 5, s = (r >> 4) & 1, lnr = r & 15;
        uint4 k0v = *(const uint4*)(Kp + (size_t)row * Hq);
        uint4 k1v = *(const uint4*)(Kp + (size_t)row * Hq + 8);
        *(uint4*)&KsF[kt * 512 + s * 256 + lnr * 8]       = k0v;  // d 0..7
        *(uint4*)&KsF[kt * 512 + s * 256 + 128 + lnr * 8] = k1v;  // d 8..15
        uint4 v0 = *(const uint4*)(Vp + (size_t)row * Hq);
        uint4 v1 = *(const uint4*)(Vp + (size_t)row * Hq + 8);
        u16 vv[16];
        *(uint4*)&vv[0] = v0; *(uint4*)&vv[8] = v1;
#pragma unroll
        for (int d = 0; d < 16; ++d) VT[d * 520 + r] = vv[d];
    }
    __syncthreads();

    int wave = tid >> 6, lane = tid & 63;
    int quad = lane >> 4, ln = lane & 15;
    int q0w = qq * 128 + wave * 32;

    float tblf = (lane < 50) ? (deL[lane * NHq + nh] + abL[nh]) * LOG2E : 0.0f;
    int tbli = __float_as_int(tblf);
    unsigned tl = tmaskp[b * 16 + nt - 1];

    // hoisted Q B-frags (quads 2,3 supply the zero d-padding)
    half8 qf[2];
#pragma unroll
    for (int t = 0; t < 2; ++t) {
        uint4 qv = {0, 0, 0, 0};
        if (quad < 2)
            qv = *(const uint4*)(Qh + (size_t)(b * Nq + q0w + t * 16 + ln) * Hq
                                 + nh * HDq + quad * 8);
        qf[t] = *(half8*)&qv;
    }

    f32x4 zero = {0.f, 0.f, 0.f, 0.f};
    f32x4 acc[2] = {zero, zero};
    float zp[2] = {0.f, 0.f};
    _Float16* Pw = (_Float16*)&Pl[wave * 640];
    const _Float16* KsH = (const _Float16*)KsF;
    const _Float16* VTH = (const _Float16*)VT;
    const unsigned char* brow0 = binsc + ((size_t)b * 512 + (q0w + ln)) * 512;
    const unsigned char* brow1 = brow0 + (size_t)16 * 512;

    // prefetch kt=0 bias-byte dwords
    unsigned pb00 = *(const unsigned*)(brow0 + quad * 4);
    unsigned pb01 = *(const unsigned*)(brow0 + 16 + quad * 4);
    unsigned pb10 = *(const unsigned*)(brow1 + quad * 4);
    unsigned pb11 = *(const unsigned*)(brow1 + 16 + quad * 4);

    for (int kt = 0; kt < nt; ++kt) {
        int k0 = kt * 32;
        unsigned w = (kt == nt - 1) ? tl : 0u;
        unsigned cb00 = pb00, cb01 = pb01, cb10 = pb10, cb11 = pb11;
        if (kt < nt - 1) {
            pb00 = *(const unsigned*)(brow0 + k0 + 32 + quad * 4);
            pb01 = *(const unsigned*)(brow0 + k0 + 48 + quad * 4);
            pb10 = *(const unsigned*)(brow1 + k0 + 32 + quad * 4);
            pb11 = *(const unsigned*)(brow1 + k0 + 48 + quad * 4);
        }
        half8 vb = *(const half8*)(VTH + ln * 520 + k0 + quad * 8);
        half8 ka0 = {}, ka1 = {};
        if (quad < 2) {
            ka0 = *(const half8*)(KsH + kt * 512 + quad * 128 + ln * 8);
            ka1 = *(const half8*)(KsH + kt * 512 + 256 + quad * 128 + ln * 8);
        }
#pragma unroll
        for (int t = 0; t < 2; ++t) {
            unsigned bw0 = t == 0 ? cb00 : cb10;
            unsigned bw1 = t == 0 ? cb01 : cb11;
            f32x4 s0 = __builtin_amdgcn_mfma_f32_16x16x32_f16(ka0, qf[t], zero, 0, 0, 0);
            f32x4 s1 = __builtin_amdgcn_mfma_f32_16x16x32_f16(ka1, qf[t], zero, 0, 0, 0);
            float p[8];
#pragma unroll
            for (int r = 0; r < 4; ++r) {
                float bias = __int_as_float(__builtin_amdgcn_ds_bpermute(
                    (int)((bw0 >> (8 * r)) & 0xFFu), tbli));
                float sc = s0[r] + bias;
                bool m = (w >> (quad * 4 + r)) & 1u;
                p[r] = m ? 0.0f : __builtin_amdgcn_exp2f(sc);
            }
#pragma unroll
            for (int r = 0; r < 4; ++r) {
                float bias = __int_as_float(__builtin_amdgcn_ds_bpermute(
                    (int)((bw1 >> (8 * r)) & 0xFFu), tbli));
                float sc = s1[r] + bias;
                bool m = (w >> (16 + quad * 4 + r)) & 1u;
                p[4 + r] = m ? 0.0f : __builtin_amdgcn_exp2f(sc);
            }
            zp[t] += ((p[0] + p[1]) + (p[2] + p[3])) +
                     ((p[4] + p[5]) + (p[6] + p[7]));
            uint2 w0, w1;
            w0.x = pk2h(p[0], p[1]); w0.y = pk2h(p[2], p[3]);
            w1.x = pk2h(p[4], p[5]); w1.y = pk2h(p[6], p[7]);
            *(uint2*)(Pw + ln * 40 + quad * 4)      = w0;   // k = quad*4+r
            *(uint2*)(Pw + ln * 40 + 16 + quad * 4) = w1;   // k = 16+quad*4+r
            half8 pa = *(const half8*)(Pw + ln * 40 + quad * 8); // A[m=ln][k=quad*8+j]
            acc[t] = __builtin_amdgcn_mfma_f32_16x16x32_f16(pa, vb, acc[t], 0, 0, 0);
        }
    }
#pragma unroll
    for (int t = 0; t < 2; ++t) {
        zp[t] += __shfl_xor(zp[t], 16);
        zp[t] += __shfl_xor(zp[t], 32);
    }
#pragma unroll
    for (int t = 0; t < 2; ++t) {
#pragma unroll
        for (int r = 0; r < 4; ++r) {
            float zz = __shfl(zp[t], quad * 4 + r);
            float val = acc[t][r] / fmaxf(zz, 1e-35f);
            int qrow = q0w + t * 16 + quad * 4 + r;
            out[(size_t)(b * Nq + qrow) * Hq + nh * HDq + ln] = f2bf(val);
        }
    }
}

extern "C" void kernel_launch(void* const* d_in, const int* in_sizes, int n_in,
                              void* d_out, int out_size, void* d_ws, size_t ws_size,
                              hipStream_t stream) {
    const void* x  = d_in[0];
    const void* dist = d_in[1];
    const void* mask = d_in[2];
    const void* Wq = d_in[3];  const void* bq = d_in[4];
    const void* Wk = d_in[5];  const void* bk = d_in[6];
    const void* Wv = d_in[7];  const void* bv = d_in[8];
    const void* Wo = d_in[9];  const void* bo = d_in[10];
    const void* de = d_in[11]; const void* ab = d_in[12];
    const void* g1 = d_in[13]; const void* b1 = d_in[14];
    const void* g2 = d_in[15]; const void* b2 = d_in[16];
    const void* Wf1 = d_in[17]; const void* bf1 = d_in[18];
    const void* Wf2 = d_in[19]; const void* bf2 = d_in[20];

    char* ws = (char*)d_ws;
    const size_t OFF_DE   = 64;
    const size_t OFF_AB   = 5120;
    const size_t OFF_BINS = 8192;                    // binsc 8,388,608
    const size_t OFF_MSK  = OFF_BINS + 8388608;      // mbits 2 KB (4096 res)
    const size_t OFF_KIDX = OFF_MSK + 4096;          // 32768
    const size_t OFF_NKT  = OFF_KIDX + 32768;        // 256
    const size_t OFF_TM   = OFF_NKT + 256;           // 2048
    const size_t OFF_H    = OFF_TM + 4096;           // f32 8,388,608
    const size_t OFF_QKV  = OFF_H + 8388608;         // Qh,Kh,Vh f16
    const size_t OFF_ATT  = OFF_QKV + 25165824;      // u16 4,194,304
    const size_t OFF_WT   = OFF_ATT + 4194304;       // u16 1,572,864
    const size_t NEEDED   = OFF_WT + 1572864;
    if (ws_size < NEEDED) return;

    int* flag = (int*)ws;
    float* deF = (float*)(ws + OFF_DE);
    float* abF = (float*)(ws + OFF_AB);
    unsigned char* binsc = (unsigned char*)(ws + OFF_BINS);
    unsigned* mbits = (unsigned*)(ws + OFF_MSK);
    u16* kidxg = (u16*)(ws + OFF_KIDX);
    int* nkt = (int*)(ws + OFF_NKT);
    unsigned* tmask = (unsigned*)(ws + OFF_TM);
    float* h = (float*)(ws + OFF_H);
    u16* Qh = (u16*)(ws + OFF_QKV);
    u16* Kh = Qh + 2097152;
    u16* Vh = Qh + 2 * 2097152;
    u16* att = (u16*)(ws + OFF_ATT);
    u16* qkvT = (u16*)(ws + OFF_WT);
    u16* oT  = qkvT + 147456;
    u16* f1T = oT + 49152;
    u16* f2T = f1T + 393216;

    prep_kernel<<<1, 256, 0, stream>>>(x, de, ab, mask, flag, deF, abF, mbits,
                                       Bq * Nq, kidxg, nkt, tmask);
    setup2_kernel<<<3840, 256, 0, stream>>>(dist, kidxg, nkt, binsc, x, h,
                                            Wq, Wk, Wv, Wo, Wf1, Wf2,
                                            qkvT, oT, f1T, f2T, flag);
    qkv_mfma_kernel<<<512, 256, 0, stream>>>(h, qkvT, bq, bk, bv, 0,
                                             g1, b1, 0, Qh, Kh, Vh, flag);
    for (int l = 0; l < 3; ++l) {
        attn_kernel<<<1024, 256, 0, stream>>>(Qh, Kh, Vh, binsc, kidxg, nkt, tmask,
                                              deF + (long)l * 400, abF + (long)l * 8, att);
        ffglu_kernel<<<1024, 256, 0, stream>>>(
            att, oT + (size_t)l * 16384, bo, (long)l * Hq,
            h, g2, b2, (long)l * Hq,
            f1T + (size_t)l * 131072, bf1, (long)l * 1024,
            f2T + (size_t)l * 65536, bf2, (long)l * Hq,
            l == 2 ? d_out : nullptr, flag,
            l < 2 ? qkvT + (size_t)(l + 1) * 49152 : (const u16*)nullptr,
            bq, bk, bv, (long)(l + 1) * Hq,
            g1, b1, (long)(l + 1) * Hq,
            Qh, Kh, Vh);
    }
}

// Round 12
// 369.717 us; speedup vs baseline: 1.1329x; 1.1329x over previous
//
#include <hip/hip_runtime.h>
#include <stdint.h>

#define Bq 32
#define Nq 512
#define Hq 128
#define NHq 8
#define HDq 16
#define Mq (Bq * Nq)   // 16384

typedef unsigned short u16;
typedef __attribute__((ext_vector_type(8))) short short8;
typedef __attribute__((ext_vector_type(8))) _Float16 half8;
typedef __attribute__((ext_vector_type(2))) __fp16 fp16x2;
typedef __attribute__((ext_vector_type(4))) float f32x4;

#define LOG2E 1.4426950408889634f
#define QSCALE 0.36067376022224085f   // 0.25 * log2(e)

// ---------- dtype-flex helpers (flag: 1 = inputs are bf16, 0 = f32) ----------
__device__ __forceinline__ float bf2f(u16 v) {
    return __uint_as_float(((unsigned int)v) << 16);
}
__device__ __forceinline__ float ldin(const void* p, long idx, int bf) {
    if (bf) return bf2f(((const u16*)p)[idx]);
    return ((const float*)p)[idx];
}
__device__ __forceinline__ u16 f2bf(float v) {   // RNE
    unsigned int u = __float_as_uint(v);
    return (u16)((u + 0x7FFFu + ((u >> 16) & 1u)) >> 16);
}
__device__ __forceinline__ u16 f2h(float v) {    // f32 -> f16 bits (RNE)
    _Float16 h = (_Float16)v;
    return *(u16*)&h;
}
__device__ __forceinline__ unsigned pk2h(float a, float b) {  // packed f16 pair bits
    fp16x2 c = __builtin_amdgcn_cvt_pkrtz(a, b);
    return *(unsigned*)&c;
}

// ---------- merged prep: dtype detect + converts + mask bits + kprep ----------
__global__ void prep_kernel(const void* xraw, const void* de, const void* ab,
                            const void* mraw, int* flag, float* deo, float* abo,
                            unsigned* mbits, int n,
                            u16* __restrict__ kidxg, int* __restrict__ nkt,
                            unsigned* __restrict__ tmask) {
    __shared__ int cnt, orA, orB, orC, orD;
    __shared__ unsigned smb[512];
    int tid = threadIdx.x;
    if (tid == 0) { cnt = 0; orA = 0; orB = 0; orC = 0; orD = 0; }
    __syncthreads();
    const u16* u = (const u16*)xraw;
    int good = 0;
    for (int i = tid; i < 1024; i += 256) {
        u16 v = u[i];
        int e = (v >> 7) & 0xFF;
        if (v == 0 || (e >= 90 && e <= 141)) good++;
    }
    atomicAdd(&cnt, good);
    const uint4* p4 = (const uint4*)mraw;
    unsigned a = 0, b = 0, c = 0, d = 0;
    for (int i = tid; i < n / 16; i += 256) {
        uint4 w = p4[i];
        unsigned all = w.x | w.y | w.z | w.w;
        a |= all & 0xFEFEFEFEu;
        b |= all & 0x0000FF00u;
        c |= all & 0xFFFFFF00u;
        d |= w.y | w.w;
    }
    if (a) atomicOr(&orA, 1);
    if (b) atomicOr(&orB, 1);
    if (c) atomicOr(&orC, 1);
    if (d) atomicOr(&orD, 1);
    __syncthreads();
    int bf = (cnt >= 900);
    if (tid == 0) *flag = bf;
    int mode;  // 0 bool8, 1 int32, 2 int64, 3 bf16, 4 f32
    if (orA) mode = orB ? 3 : 4;
    else if (orC) mode = 0;
    else mode = orD ? 1 : 2;
    for (int i = tid; i < 1200; i += 256) deo[i] = ldin(de, i, bf);
    if (tid < 24) abo[tid] = ldin(ab, tid, bf);
    const unsigned char* p = (const unsigned char*)mraw;
    for (int wI = tid; wI < n / 32; wI += 256) {
        unsigned word = 0;
        for (int j = 0; j < 32; ++j) {
            int i = wI * 32 + j;
            int v;
            switch (mode) {
                case 0: v = p[i]; break;
                case 1: v = ((const int*)p)[i]; break;
                case 2: v = (int)((const long long*)p)[i]; break;
                case 3: v = ((const u16*)p)[i] != 0; break;
                default: v = (((const float*)p)[i] != 0.0f); break;
            }
            if (v) word |= 1u << j;
        }
        mbits[wI] = word;
        smb[wI] = word;
    }
    __syncthreads();
    // --- kprep fold: 64-lane groups sweep batches ---
    int lane = tid & 63;
    for (int bb = tid >> 6; bb < 32; bb += 4) {
        int pos_base = 0;
        for (int w = 0; w < 8; ++w) {
            unsigned lo = smb[bb * 16 + 2 * w], hi = smb[bb * 16 + 2 * w + 1];
            unsigned long long word = ((unsigned long long)hi << 32) | lo;
            unsigned long long un = ~word;   // 1 = unmasked
            int bit = (int)((un >> lane) & 1ull);
            unsigned long long before = un & ((1ull << lane) - 1ull);
            int pos = pos_base + __popcll(before);
            if (bit) kidxg[bb * 512 + pos] = (u16)(w * 64 + lane);
            pos_base += __popcll(un);
        }
        int nk = pos_base;
        int nkp = (nk + 31) & ~31;
        if (nkp == 0) nkp = 32;
        int nt = nkp >> 5;
        for (int j = nk + lane; j < nkp; j += 64) kidxg[bb * 512 + j] = 0;
        if (lane == 0) {
            nkt[bb] = nt;
            for (int t = 0; t < 16; ++t) tmask[bb * 16 + t] = 0;
            int rem = nk & 31;
            if (rem) tmask[bb * 16 + nt - 1] = 0xFFFFFFFFu << rem;
            if (nk == 0) tmask[bb * 16] = 0xFFFFFFFFu;
        }
    }
}

// ---------- setup2: binsc + init + wtrans fused (range-switched grid) ------
// [0,2048): binsc. [2048,3072): init copy. [3072,3840): wtrans.
__global__ __launch_bounds__(256) void setup2_kernel(
    const void* __restrict__ dist, const u16* __restrict__ kidxg,
    const int* __restrict__ nktp, unsigned char* __restrict__ binsc,
    const void* x, float* __restrict__ h,
    const void* Wqr, const void* Wkr, const void* Wvr, const void* Wor,
    const void* Wf1r, const void* Wf2r,
    u16* qkvT, u16* oT, u16* f1T, u16* f2T, const int* flagp) {
    __shared__ u16 kl[512];
    __shared__ int ntS;
    __shared__ u16 Ts[32][33];
    int id = blockIdx.x;
    int tid = threadIdx.x;
    int bf = *flagp;
    if (id < 2048) {
        int b = id >> 6;
        int q0 = (id & 63) * 8;
        if (tid == 0) ntS = nktp[b];
        kl[tid] = kidxg[b * 512 + tid];
        kl[tid + 256] = kidxg[b * 512 + tid + 256];
        __syncthreads();
        int nkp = ntS * 32;
        for (int rq = 0; rq < 8; ++rq) {
            int q = q0 + rq;
            long rowoff = ((long)b * 512 + q) * 512;
            for (int j = tid; j < nkp; j += 256) {
                float d = ldin(dist, rowoff + kl[j], bf);
                int v = (int)(d * 10.0f);
                v = v < 0 ? 0 : (v > 49 ? 49 : v);
                binsc[((size_t)b * 512 + q) * 512 + j] = (unsigned char)(v << 2);
            }
        }
    } else if (id < 3072) {
        int i = (id - 2048) * 256 + tid;
        long base = (long)i * 8;
        if (bf) {
            uint4 w = ((const uint4*)x)[i];
            const u16* ws = (const u16*)&w;
            float o[8];
#pragma unroll
            for (int k = 0; k < 8; ++k) o[k] = bf2f(ws[k]);
            *(float4*)&h[base] = *(float4*)&o[0];
            *(float4*)&h[base + 4] = *(float4*)&o[4];
        } else {
            float4 a = ((const float4*)x)[2 * i];
            float4 b2v = ((const float4*)x)[2 * i + 1];
            *(float4*)&h[base] = a;
            *(float4*)&h[base + 4] = b2v;
        }
    } else {
        int bid = id - 3072;
        int l = bid >> 8, r = bid & 255;
        const void* src; u16* dst; long soff, doff; int Kd, Nd, t;
        if (r < 64) {
            int mat = r >> 4; t = r & 15; Kd = 128; Nd = 128;
            soff = (long)l * 16384;
            if (mat == 0)      { src = Wqr; dst = qkvT; doff = (long)l * 49152; }
            else if (mat == 1) { src = Wkr; dst = qkvT; doff = (long)l * 49152 + 16384; }
            else if (mat == 2) { src = Wvr; dst = qkvT; doff = (long)l * 49152 + 32768; }
            else               { src = Wor; dst = oT;   doff = (long)l * 16384; }
        } else if (r < 192) {
            t = r - 64; Kd = 128; Nd = 1024;
            src = Wf1r; soff = (long)l * 131072; dst = f1T; doff = (long)l * 131072;
        } else {
            t = r - 192; Kd = 512; Nd = 128;
            src = Wf2r; soff = (long)l * 65536; dst = f2T; doff = (long)l * 65536;
        }
        int ntile = Nd >> 5;
        int tk = t / ntile, tn = t % ntile;
        int rr = tid >> 3, cc0 = (tid & 7) * 4;
#pragma unroll
        for (int i = 0; i < 4; ++i) {
            long idx = soff + (long)(tk * 32 + rr) * Nd + tn * 32 + cc0 + i;
            Ts[rr][cc0 + i] = f2bf(ldin(src, idx, bf));
        }
        __syncthreads();
#pragma unroll
        for (int i = 0; i < 4; ++i) {
            long idx = doff + (long)(tn * 32 + rr) * Kd + tk * 32 + cc0 + i;
            dst[idx] = Ts[cc0 + i][rr];
        }
    }
}

// ===== QKV (layer 0 only): LN once, Q/K/V looped, B streamed from L2 =====
__global__ __launch_bounds__(256, 4) void qkv_mfma_kernel(
    const float* __restrict__ h, const u16* __restrict__ qkvT_l,
    const void* bqr, const void* bkr, const void* bvr, long bOff,
    const void* g1raw, const void* b1raw, long lnOff,
    u16* __restrict__ Qo, u16* __restrict__ Ko, u16* __restrict__ Vo,
    const int* flagp) {
    __shared__ __align__(16) u16 As[32][136];
    int tid = threadIdx.x;
    int m0 = blockIdx.x * 32;
    int bf = *flagp;
    {
        int row = tid >> 3, c0 = (tid & 7) * 16;
        const float* hp = h + (size_t)(m0 + row) * 128 + c0;
        float4 f0 = *(const float4*)(hp);
        float4 f1 = *(const float4*)(hp + 4);
        float4 f2 = *(const float4*)(hp + 8);
        float4 f3 = *(const float4*)(hp + 12);
        float vv[16] = {f0.x, f0.y, f0.z, f0.w, f1.x, f1.y, f1.z, f1.w,
                        f2.x, f2.y, f2.z, f2.w, f3.x, f3.y, f3.z, f3.w};
        float s = 0.f, s2 = 0.f;
#pragma unroll
        for (int k = 0; k < 16; ++k) { s += vv[k]; s2 += vv[k] * vv[k]; }
#pragma unroll
        for (int o = 1; o < 8; o <<= 1) {
            s += __shfl_xor(s, o);
            s2 += __shfl_xor(s2, o);
        }
        float mu = s * (1.0f / 128.0f);
        float var = fmaxf(s2 * (1.0f / 128.0f) - mu * mu, 0.0f);
        float rstd = rsqrtf(var + 1e-5f);
        u16 tmp[16];
#pragma unroll
        for (int k = 0; k < 16; ++k) {
            float g = ldin(g1raw, lnOff + c0 + k, bf);
            float b = ldin(b1raw, lnOff + c0 + k, bf);
            tmp[k] = f2bf((vv[k] - mu) * rstd * g + b);
        }
        *(uint4*)&As[row][c0]     = *(uint4*)&tmp[0];
        *(uint4*)&As[row][c0 + 8] = *(uint4*)&tmp[8];
    }
    __syncthreads();
    int wave = tid >> 6, lane = tid & 63;
    int q = lane >> 4, ln = lane & 15;
    int nb = wave * 32;
    f32x4 zero = {0.f, 0.f, 0.f, 0.f};
#pragma unroll
    for (int mat = 0; mat < 3; ++mat) {
        const u16* WT = qkvT_l + (size_t)mat * 16384;
        const void* braw = mat == 0 ? bqr : (mat == 1 ? bkr : bvr);
        u16* C = mat == 0 ? Qo : (mat == 1 ? Ko : Vo);
        float scale = mat == 0 ? QSCALE : 1.0f;
        short8 bfr[2][4];
#pragma unroll
        for (int t = 0; t < 2; ++t)
#pragma unroll
            for (int k4 = 0; k4 < 4; ++k4)
                bfr[t][k4] = *(const short8*)(WT + (size_t)(nb + t * 16 + ln) * 128
                                              + k4 * 32 + q * 8);
        f32x4 acc[2][2];
#pragma unroll
        for (int i = 0; i < 2; ++i)
#pragma unroll
            for (int j = 0; j < 2; ++j) acc[i][j] = zero;
#pragma unroll
        for (int k4 = 0; k4 < 4; ++k4) {
            short8 af0 = *(const short8*)&As[ln][k4 * 32 + q * 8];
            short8 af1 = *(const short8*)&As[16 + ln][k4 * 32 + q * 8];
#pragma unroll
            for (int t = 0; t < 2; ++t) {
                acc[0][t] = __builtin_amdgcn_mfma_f32_16x16x32_bf16(
                    af0, bfr[t][k4], acc[0][t], 0, 0, 0);
                acc[1][t] = __builtin_amdgcn_mfma_f32_16x16x32_bf16(
                    af1, bfr[t][k4], acc[1][t], 0, 0, 0);
            }
        }
#pragma unroll
        for (int t = 0; t < 2; ++t) {
            int n = nb + t * 16 + ln;
            float bias = ldin(braw, bOff + n, bf);
#pragma unroll
            for (int mi = 0; mi < 2; ++mi)
#pragma unroll
                for (int r = 0; r < 4; ++r) {
                    int m = m0 + mi * 16 + q * 4 + r;
                    C[(size_t)m * 128 + n] = f2h((acc[mi][t][r] + bias) * scale);
                }
        }
    }
}

// ===== fused FFN v6: 32-row tiles (keeps 2x B-reuse), ff1->ff2 interleaved ==
// per 64-col chunk through a small double-buffered vgc => LDS 18.5 KB =>
// 4 blocks/CU (16 waves/CU). Same math order as round 7 (bitwise identical).
__global__ __launch_bounds__(256, 4) void ffglu_kernel(
    const u16* __restrict__ att, const u16* __restrict__ oT_l,
    const void* __restrict__ bo, long boOff, float* __restrict__ h,
    const void* g2, const void* b2, long ln2Off,
    const u16* __restrict__ f1T_l, const void* __restrict__ bf1r, long bf1Off,
    const u16* __restrict__ f2T_l, const void* __restrict__ bf2r, long bf2Off,
    void* __restrict__ outp, const int* flagp,
    const u16* __restrict__ qkvTn,    // next layer qkvT (or nullptr)
    const void* bqr, const void* bkr, const void* bvr, long bOffN,
    const void* g1, const void* b1, long ln1OffN,
    u16* __restrict__ Qo, u16* __restrict__ Ko, u16* __restrict__ Vo) {
    __shared__ __align__(16) u16 As[32][136];    // att stage / hn2 / hn1-next
    __shared__ __align__(16) u16 vgc[2][32][72]; // GLU chunk, double-buffered
    __shared__ float stats[32][4][2];
    int tid = threadIdx.x;
    int m0 = blockIdx.x * 32;
    int wave = tid >> 6, lane = tid & 63;
    int q = lane >> 4, ln = lane & 15;
    int nb = wave * 32;
    int bf = *flagp;
    f32x4 zero = {0.f, 0.f, 0.f, 0.f};

    // ---- stage att [32][128] ----
#pragma unroll
    for (int i = 0; i < 2; ++i) {
        int idx = tid + i * 256; int r = idx >> 4, c = (idx & 15) << 3;
        *(uint4*)&As[r][c] = *(const uint4*)(att + (size_t)(m0 + r) * 128 + c);
    }
    __syncthreads();                                   // B1
    // ---- o-proj: B streamed ----
    f32x4 acc[2][2];
#pragma unroll
    for (int i = 0; i < 2; ++i)
#pragma unroll
        for (int j = 0; j < 2; ++j) acc[i][j] = zero;
    {
        short8 bfr[2][4];
#pragma unroll
        for (int t = 0; t < 2; ++t)
#pragma unroll
            for (int k4 = 0; k4 < 4; ++k4)
                bfr[t][k4] = *(const short8*)(oT_l + (size_t)(nb + t * 16 + ln) * 128
                                              + k4 * 32 + q * 8);
#pragma unroll
        for (int k4 = 0; k4 < 4; ++k4) {
            short8 af0 = *(const short8*)&As[ln][k4 * 32 + q * 8];
            short8 af1 = *(const short8*)&As[16 + ln][k4 * 32 + q * 8];
#pragma unroll
            for (int t = 0; t < 2; ++t) {
                acc[0][t] = __builtin_amdgcn_mfma_f32_16x16x32_bf16(
                    af0, bfr[t][k4], acc[0][t], 0, 0, 0);
                acc[1][t] = __builtin_amdgcn_mfma_f32_16x16x32_bf16(
                    af1, bfr[t][k4], acc[1][t], 0, 0, 0);
            }
        }
    }
    // ---- epilogue: +bias +resid(h) -> h1 regs; LN2 partial stats ----
    float h1[2][2][4];
    float srow[2][4], s2row[2][4];
#pragma unroll
    for (int mi = 0; mi < 2; ++mi)
#pragma unroll
        for (int r = 0; r < 4; ++r) { srow[mi][r] = 0.f; s2row[mi][r] = 0.f; }
#pragma unroll
    for (int t = 0; t < 2; ++t) {
        int n = nb + t * 16 + ln;
        float bias = ldin(bo, boOff + n, bf);
#pragma unroll
        for (int mi = 0; mi < 2; ++mi)
#pragma unroll
            for (int r = 0; r < 4; ++r) {
                float v = acc[mi][t][r] + bias +
                          h[(size_t)(m0 + mi * 16 + q * 4 + r) * 128 + n];
                h1[mi][t][r] = v;
                srow[mi][r] += v; s2row[mi][r] += v * v;
            }
    }
#pragma unroll
    for (int mi = 0; mi < 2; ++mi)
#pragma unroll
        for (int r = 0; r < 4; ++r)
#pragma unroll
            for (int o = 1; o < 16; o <<= 1) {
                srow[mi][r] += __shfl_xor(srow[mi][r], o);
                s2row[mi][r] += __shfl_xor(s2row[mi][r], o);
            }
    if (ln == 0) {
#pragma unroll
        for (int mi = 0; mi < 2; ++mi)
#pragma unroll
            for (int r = 0; r < 4; ++r) {
                stats[mi * 16 + q * 4 + r][wave][0] = srow[mi][r];
                stats[mi * 16 + q * 4 + r][wave][1] = s2row[mi][r];
            }
    }
    __syncthreads();                                   // B2
    // ---- LN2 -> hn2 (As overlay) ----
    float mu[2][4], rs[2][4];
#pragma unroll
    for (int mi = 0; mi < 2; ++mi)
#pragma unroll
        for (int r = 0; r < 4; ++r) {
            int row = mi * 16 + q * 4 + r;
            float s = (stats[row][0][0] + stats[row][1][0]) +
                      (stats[row][2][0] + stats[row][3][0]);
            float s2 = (stats[row][0][1] + stats[row][1][1]) +
                       (stats[row][2][1] + stats[row][3][1]);
            mu[mi][r] = s * (1.0f / 128.0f);
            float var = fmaxf(s2 * (1.0f / 128.0f) - mu[mi][r] * mu[mi][r], 0.0f);
            rs[mi][r] = rsqrtf(var + 1e-5f);
        }
#pragma unroll
    for (int t = 0; t < 2; ++t) {
        int n = nb + t * 16 + ln;
        float g = ldin(g2, ln2Off + n, bf), bb = ldin(b2, ln2Off + n, bf);
#pragma unroll
        for (int mi = 0; mi < 2; ++mi)
#pragma unroll
            for (int r = 0; r < 4; ++r)
                As[mi * 16 + q * 4 + r][n] =
                    f2bf((h1[mi][t][r] - mu[mi][r]) * rs[mi][r] * g + bb);
    }
    __syncthreads();                                   // B3
    // ---- ff1 + ff2 interleaved: 8 chunks of 64 GLU cols; each chunk's ----
    // GLU output goes through vgc (double-buffered) straight into ff2 accs.
    int nb16 = wave * 16;
    f32x4 accF[2][2];
#pragma unroll
    for (int i = 0; i < 2; ++i)
#pragma unroll
        for (int j = 0; j < 2; ++j) accF[i][j] = zero;
    for (int ch = 0; ch < 8; ++ch) {
        int buf = ch & 1;
        int arow = ch * 64 + nb16;
        short8 ba[4], bb8[4];
#pragma unroll
        for (int k4 = 0; k4 < 4; ++k4) {
            ba[k4]  = *(const short8*)(f1T_l + (size_t)(arow + ln) * 128
                                       + k4 * 32 + q * 8);
            bb8[k4] = *(const short8*)(f1T_l + (size_t)(512 + arow + ln) * 128
                                       + k4 * 32 + q * 8);
        }
        f32x4 aA[2] = {zero, zero}, aB[2] = {zero, zero};
#pragma unroll
        for (int k4 = 0; k4 < 4; ++k4) {
            short8 af0 = *(const short8*)&As[ln][k4 * 32 + q * 8];
            short8 af1 = *(const short8*)&As[16 + ln][k4 * 32 + q * 8];
            aA[0] = __builtin_amdgcn_mfma_f32_16x16x32_bf16(af0, ba[k4], aA[0], 0, 0, 0);
            aA[1] = __builtin_amdgcn_mfma_f32_16x16x32_bf16(af1, ba[k4], aA[1], 0, 0, 0);
            aB[0] = __builtin_amdgcn_mfma_f32_16x16x32_bf16(af0, bb8[k4], aB[0], 0, 0, 0);
            aB[1] = __builtin_amdgcn_mfma_f32_16x16x32_bf16(af1, bb8[k4], aB[1], 0, 0, 0);
        }
        int n = arow + ln;          // global GLU col
        int lc = nb16 + ln;         // col within chunk (0..63)
        float bA = ldin(bf1r, bf1Off + n, bf);
        float bB = ldin(bf1r, bf1Off + 512 + n, bf);
#pragma unroll
        for (int mi = 0; mi < 2; ++mi)
#pragma unroll
            for (int r = 0; r < 4; ++r) {
                float ua = aA[mi][r] + bA, ub = aB[mi][r] + bB;
                vgc[buf][mi * 16 + q * 4 + r][lc] = f2bf(ua / (1.0f + __expf(-ub)));
            }
        __syncthreads();            // chunk barrier (dbuf makes 1/chunk safe)
        // ff2 partial for this chunk's k-range [ch*64, ch*64+64)
        short8 bfr[2][2];
#pragma unroll
        for (int t = 0; t < 2; ++t)
#pragma unroll
            for (int k2 = 0; k2 < 2; ++k2)
                bfr[t][k2] = *(const short8*)(f2T_l + (size_t)(nb + t * 16 + ln) * 512
                                              + ch * 64 + k2 * 32 + q * 8);
#pragma unroll
        for (int k2 = 0; k2 < 2; ++k2) {
            short8 af0 = *(const short8*)&vgc[buf][ln][k2 * 32 + q * 8];
            short8 af1 = *(const short8*)&vgc[buf][16 + ln][k2 * 32 + q * 8];
#pragma unroll
            for (int t = 0; t < 2; ++t) {
                accF[0][t] = __builtin_amdgcn_mfma_f32_16x16x32_bf16(
                    af0, bfr[t][k2], accF[0][t], 0, 0, 0);
                accF[1][t] = __builtin_amdgcn_mfma_f32_16x16x32_bf16(
                    af1, bfr[t][k2], accF[1][t], 0, 0, 0);
            }
        }
    }
    // ---- epilogue: +bias +resid -> h (and h1 regs for next-layer LN1) ----
#pragma unroll
    for (int t = 0; t < 2; ++t) {
        int n = nb + t * 16 + ln;
        float bias = ldin(bf2r, bf2Off + n, bf);
#pragma unroll
        for (int mi = 0; mi < 2; ++mi)
#pragma unroll
            for (int r = 0; r < 4; ++r) {
                int m = m0 + mi * 16 + q * 4 + r;
                float v = accF[mi][t][r] + bias + h1[mi][t][r];
                h[(size_t)m * 128 + n] = v;
                h1[mi][t][r] = v;   // reuse for LN1-next
                if (outp) {
                    if (bf) ((u16*)outp)[(size_t)m * 128 + n] = f2bf(v);
                    else ((float*)outp)[(size_t)m * 128 + n] = v;
                }
            }
    }
    if (!qkvTn) return;
    // ---- LN1 (next layer) stats ----
#pragma unroll
    for (int mi = 0; mi < 2; ++mi)
#pragma unroll
        for (int r = 0; r < 4; ++r) { srow[mi][r] = 0.f; s2row[mi][r] = 0.f; }
#pragma unroll
    for (int t = 0; t < 2; ++t)
#pragma unroll
        for (int mi = 0; mi < 2; ++mi)
#pragma unroll
            for (int r = 0; r < 4; ++r) {
                float v = h1[mi][t][r];
                srow[mi][r] += v; s2row[mi][r] += v * v;
            }
#pragma unroll
    for (int mi = 0; mi < 2; ++mi)
#pragma unroll
        for (int r = 0; r < 4; ++r)
#pragma unroll
            for (int o = 1; o < 16; o <<= 1) {
                srow[mi][r] += __shfl_xor(srow[mi][r], o);
                s2row[mi][r] += __shfl_xor(s2row[mi][r], o);
            }
    if (ln == 0) {
#pragma unroll
        for (int mi = 0; mi < 2; ++mi)
#pragma unroll
            for (int r = 0; r < 4; ++r) {
                stats[mi * 16 + q * 4 + r][wave][0] = srow[mi][r];
                stats[mi * 16 + q * 4 + r][wave][1] = s2row[mi][r];
            }
    }
    __syncthreads();                                   // B5
#pragma unroll
    for (int mi = 0; mi < 2; ++mi)
#pragma unroll
        for (int r = 0; r < 4; ++r) {
            int row = mi * 16 + q * 4 + r;
            float s = (stats[row][0][0] + stats[row][1][0]) +
                      (stats[row][2][0] + stats[row][3][0]);
            float s2 = (stats[row][0][1] + stats[row][1][1]) +
                       (stats[row][2][1] + stats[row][3][1]);
            mu[mi][r] = s * (1.0f / 128.0f);
            float var = fmaxf(s2 * (1.0f / 128.0f) - mu[mi][r] * mu[mi][r], 0.0f);
            rs[mi][r] = rsqrtf(var + 1e-5f);
        }
#pragma unroll
    for (int t = 0; t < 2; ++t) {
        int n = nb + t * 16 + ln;
        float g = ldin(g1, ln1OffN + n, bf), bb = ldin(b1, ln1OffN + n, bf);
#pragma unroll
        for (int mi = 0; mi < 2; ++mi)
#pragma unroll
            for (int r = 0; r < 4; ++r)
                As[mi * 16 + q * 4 + r][n] =
                    f2bf((h1[mi][t][r] - mu[mi][r]) * rs[mi][r] * g + bb);
    }
    __syncthreads();                                   // B6
    // ---- next-layer QKV: B streamed, same pattern as standalone ----
#pragma unroll
    for (int mat = 0; mat < 3; ++mat) {
        const u16* WT = qkvTn + (size_t)mat * 16384;
        const void* braw = mat == 0 ? bqr : (mat == 1 ? bkr : bvr);
        u16* C = mat == 0 ? Qo : (mat == 1 ? Ko : Vo);
        float scale = mat == 0 ? QSCALE : 1.0f;
        short8 bfr[2][4];
#pragma unroll
        for (int t = 0; t < 2; ++t)
#pragma unroll
            for (int k4 = 0; k4 < 4; ++k4)
                bfr[t][k4] = *(const short8*)(WT + (size_t)(nb + t * 16 + ln) * 128
                                              + k4 * 32 + q * 8);
        f32x4 aq[2][2];
#pragma unroll
        for (int i = 0; i < 2; ++i)
#pragma unroll
            for (int j = 0; j < 2; ++j) aq[i][j] = zero;
#pragma unroll
        for (int k4 = 0; k4 < 4; ++k4) {
            short8 af0 = *(const short8*)&As[ln][k4 * 32 + q * 8];
            short8 af1 = *(const short8*)&As[16 + ln][k4 * 32 + q * 8];
#pragma unroll
            for (int t = 0; t < 2; ++t) {
                aq[0][t] = __builtin_amdgcn_mfma_f32_16x16x32_bf16(
                    af0, bfr[t][k4], aq[0][t], 0, 0, 0);
                aq[1][t] = __builtin_amdgcn_mfma_f32_16x16x32_bf16(
                    af1, bfr[t][k4], aq[1][t], 0, 0, 0);
            }
        }
#pragma unroll
        for (int t = 0; t < 2; ++t) {
            int n = nb + t * 16 + ln;
            float bias = ldin(braw, bOffN + n, bf);
#pragma unroll
            for (int mi = 0; mi < 2; ++mi)
#pragma unroll
                for (int r = 0; r < 4; ++r) {
                    int m = m0 + mi * 16 + q * 4 + r;
                    C[(size_t)m * 128 + n] = f2h((aq[mi][t][r] + bias) * scale);
                }
        }
    }
}

// ========== attention v6: exp2-domain softmax (Q pre-scaled by log2e) =======
__global__ __launch_bounds__(256, 4) void attn_kernel(
    const u16* __restrict__ Qh, const u16* __restrict__ Kh,
    const u16* __restrict__ Vh, const unsigned char* __restrict__ binsc,
    const u16* __restrict__ kidxg, const int* __restrict__ nktp,
    const unsigned* __restrict__ tmaskp, const float* __restrict__ deL,
    const float* __restrict__ abL, u16* __restrict__ out) {
    // de-swizzle: heads of one (b,qq) share id%8 -> same XCD L2 for binsc
    int id = blockIdx.x;
    int c = id & 7, t5 = id >> 3;
    int nh = t5 & 7;
    int pair = ((t5 >> 3) << 3) | c;
    int b = pair >> 2, qq = pair & 3;

    __shared__ __align__(16) u16 KsF[8192];      // frag-major K, 16 KB
    __shared__ __align__(16) u16 VT[16 * 520];   // V^T rows 520 f16, 16.25 KB
    __shared__ __align__(16) u16 Pl[4 * 16 * 40];// per-wave P tile, 5 KB

    int tid = threadIdx.x;
    int nt = __builtin_amdgcn_readfirstlane(nktp[b]);
    int nkp = nt * 32;
    const u16* Kp = Kh + (size_t)(b * Nq) * Hq + nh * HDq;
    const u16* Vp = Vh + (size_t)(b * Nq) * Hq + nh * HDq;
    for (int r = tid; r < nkp; r += 256) {
        int row = kidxg[b * 512 + r];
        int kt = r >> 5, s = (r >> 4) & 1, lnr = r & 15;
        uint4 k0v = *(const uint4*)(Kp + (size_t)row * Hq);
        uint4 k1v = *(const uint4*)(Kp + (size_t)row * Hq + 8);
        *(uint4*)&KsF[kt * 512 + s * 256 + lnr * 8]       = k0v;  // d 0..7
        *(uint4*)&KsF[kt * 512 + s * 256 + 128 + lnr * 8] = k1v;  // d 8..15
        uint4 v0 = *(const uint4*)(Vp + (size_t)row * Hq);
        uint4 v1 = *(const uint4*)(Vp + (size_t)row * Hq + 8);
        u16 vv[16];
        *(uint4*)&vv[0] = v0; *(uint4*)&vv[8] = v1;
#pragma unroll
        for (int d = 0; d < 16; ++d) VT[d * 520 + r] = vv[d];
    }
    __syncthreads();

    int wave = tid >> 6, lane = tid & 63;
    int quad = lane >> 4, ln = lane & 15;
    int q0w = qq * 128 + wave * 32;

    float tblf = (lane < 50) ? (deL[lane * NHq + nh] + abL[nh]) * LOG2E : 0.0f;
    int tbli = __float_as_int(tblf);
    unsigned tl = tmaskp[b * 16 + nt - 1];

    // hoisted Q B-frags (quads 2,3 supply the zero d-padding)
    half8 qf[2];
#pragma unroll
    for (int t = 0; t < 2; ++t) {
        uint4 qv = {0, 0, 0, 0};
        if (quad < 2)
            qv = *(const uint4*)(Qh + (size_t)(b * Nq + q0w + t * 16 + ln) * Hq
                                 + nh * HDq + quad * 8);
        qf[t] = *(half8*)&qv;
    }

    f32x4 zero = {0.f, 0.f, 0.f, 0.f};
    f32x4 acc[2] = {zero, zero};
    float zp[2] = {0.f, 0.f};
    _Float16* Pw = (_Float16*)&Pl[wave * 640];
    const _Float16* KsH = (const _Float16*)KsF;
    const _Float16* VTH = (const _Float16*)VT;
    const unsigned char* brow0 = binsc + ((size_t)b * 512 + (q0w + ln)) * 512;
    const unsigned char* brow1 = brow0 + (size_t)16 * 512;

    // prefetch kt=0 bias-byte dwords
    unsigned pb00 = *(const unsigned*)(brow0 + quad * 4);
    unsigned pb01 = *(const unsigned*)(brow0 + 16 + quad * 4);
    unsigned pb10 = *(const unsigned*)(brow1 + quad * 4);
    unsigned pb11 = *(const unsigned*)(brow1 + 16 + quad * 4);

    for (int kt = 0; kt < nt; ++kt) {
        int k0 = kt * 32;
        unsigned w = (kt == nt - 1) ? tl : 0u;
        unsigned cb00 = pb00, cb01 = pb01, cb10 = pb10, cb11 = pb11;
        if (kt < nt - 1) {
            pb00 = *(const unsigned*)(brow0 + k0 + 32 + quad * 4);
            pb01 = *(const unsigned*)(brow0 + k0 + 48 + quad * 4);
            pb10 = *(const unsigned*)(brow1 + k0 + 32 + quad * 4);
            pb11 = *(const unsigned*)(brow1 + k0 + 48 + quad * 4);
        }
        half8 vb = *(const half8*)(VTH + ln * 520 + k0 + quad * 8);
        half8 ka0 = {}, ka1 = {};
        if (quad < 2) {
            ka0 = *(const half8*)(KsH + kt * 512 + quad * 128 + ln * 8);
            ka1 = *(const half8*)(KsH + kt * 512 + 256 + quad * 128 + ln * 8);
        }
#pragma unroll
        for (int t = 0; t < 2; ++t) {
            unsigned bw0 = t == 0 ? cb00 : cb10;
            unsigned bw1 = t == 0 ? cb01 : cb11;
            f32x4 s0 = __builtin_amdgcn_mfma_f32_16x16x32_f16(ka0, qf[t], zero, 0, 0, 0);
            f32x4 s1 = __builtin_amdgcn_mfma_f32_16x16x32_f16(ka1, qf[t], zero, 0, 0, 0);
            float p[8];
#pragma unroll
            for (int r = 0; r < 4; ++r) {
                float bias = __int_as_float(__builtin_amdgcn_ds_bpermute(
                    (int)((bw0 >> (8 * r)) & 0xFFu), tbli));
                float sc = s0[r] + bias;
                bool m = (w >> (quad * 4 + r)) & 1u;
                p[r] = m ? 0.0f : __builtin_amdgcn_exp2f(sc);
            }
#pragma unroll
            for (int r = 0; r < 4; ++r) {
                float bias = __int_as_float(__builtin_amdgcn_ds_bpermute(
                    (int)((bw1 >> (8 * r)) & 0xFFu), tbli));
                float sc = s1[r] + bias;
                bool m = (w >> (16 + quad * 4 + r)) & 1u;
                p[4 + r] = m ? 0.0f : __builtin_amdgcn_exp2f(sc);
            }
            zp[t] += ((p[0] + p[1]) + (p[2] + p[3])) +
                     ((p[4] + p[5]) + (p[6] + p[7]));
            uint2 w0, w1;
            w0.x = pk2h(p[0], p[1]); w0.y = pk2h(p[2], p[3]);
            w1.x = pk2h(p[4], p[5]); w1.y = pk2h(p[6], p[7]);
            *(uint2*)(Pw + ln * 40 + quad * 4)      = w0;   // k = quad*4+r
            *(uint2*)(Pw + ln * 40 + 16 + quad * 4) = w1;   // k = 16+quad*4+r
            half8 pa = *(const half8*)(Pw + ln * 40 + quad * 8); // A[m=ln][k=quad*8+j]
            acc[t] = __builtin_amdgcn_mfma_f32_16x16x32_f16(pa, vb, acc[t], 0, 0, 0);
        }
    }
#pragma unroll
    for (int t = 0; t < 2; ++t) {
        zp[t] += __shfl_xor(zp[t], 16);
        zp[t] += __shfl_xor(zp[t], 32);
    }
#pragma unroll
    for (int t = 0; t < 2; ++t) {
#pragma unroll
        for (int r = 0; r < 4; ++r) {
            float zz = __shfl(zp[t], quad * 4 + r);
            float val = acc[t][r] / fmaxf(zz, 1e-35f);
            int qrow = q0w + t * 16 + quad * 4 + r;
            out[(size_t)(b * Nq + qrow) * Hq + nh * HDq + ln] = f2bf(val);
        }
    }
}

extern "C" void kernel_launch(void* const* d_in, const int* in_sizes, int n_in,
                              void* d_out, int out_size, void* d_ws, size_t ws_size,
                              hipStream_t stream) {
    const void* x  = d_in[0];
    const void* dist = d_in[1];
    const void* mask = d_in[2];
    const void* Wq = d_in[3];  const void* bq = d_in[4];
    const void* Wk = d_in[5];  const void* bk = d_in[6];
    const void* Wv = d_in[7];  const void* bv = d_in[8];
    const void* Wo = d_in[9];  const void* bo = d_in[10];
    const void* de = d_in[11]; const void* ab = d_in[12];
    const void* g1 = d_in[13]; const void* b1 = d_in[14];
    const void* g2 = d_in[15]; const void* b2 = d_in[16];
    const void* Wf1 = d_in[17]; const void* bf1 = d_in[18];
    const void* Wf2 = d_in[19]; const void* bf2 = d_in[20];

    char* ws = (char*)d_ws;
    const size_t OFF_DE   = 64;
    const size_t OFF_AB   = 5120;
    const size_t OFF_BINS = 8192;                    // binsc 8,388,608
    const size_t OFF_MSK  = OFF_BINS + 8388608;      // mbits 2 KB (4096 res)
    const size_t OFF_KIDX = OFF_MSK + 4096;          // 32768
    const size_t OFF_NKT  = OFF_KIDX + 32768;        // 256
    const size_t OFF_TM   = OFF_NKT + 256;           // 2048
    const size_t OFF_H    = OFF_TM + 4096;           // f32 8,388,608
    const size_t OFF_QKV  = OFF_H + 8388608;         // Qh,Kh,Vh f16
    const size_t OFF_ATT  = OFF_QKV + 25165824;      // u16 4,194,304
    const size_t OFF_WT   = OFF_ATT + 4194304;       // u16 1,572,864
    const size_t NEEDED   = OFF_WT + 1572864;
    if (ws_size < NEEDED) return;

    int* flag = (int*)ws;
    float* deF = (float*)(ws + OFF_DE);
    float* abF = (float*)(ws + OFF_AB);
    unsigned char* binsc = (unsigned char*)(ws + OFF_BINS);
    unsigned* mbits = (unsigned*)(ws + OFF_MSK);
    u16* kidxg = (u16*)(ws + OFF_KIDX);
    int* nkt = (int*)(ws + OFF_NKT);
    unsigned* tmask = (unsigned*)(ws + OFF_TM);
    float* h = (float*)(ws + OFF_H);
    u16* Qh = (u16*)(ws + OFF_QKV);
    u16* Kh = Qh + 2097152;
    u16* Vh = Qh + 2 * 2097152;
    u16* att = (u16*)(ws + OFF_ATT);
    u16* qkvT = (u16*)(ws + OFF_WT);
    u16* oT  = qkvT + 147456;
    u16* f1T = oT + 49152;
    u16* f2T = f1T + 393216;

    prep_kernel<<<1, 256, 0, stream>>>(x, de, ab, mask, flag, deF, abF, mbits,
                                       Bq * Nq, kidxg, nkt, tmask);
    setup2_kernel<<<3840, 256, 0, stream>>>(dist, kidxg, nkt, binsc, x, h,
                                            Wq, Wk, Wv, Wo, Wf1, Wf2,
                                            qkvT, oT, f1T, f2T, flag);
    qkv_mfma_kernel<<<512, 256, 0, stream>>>(h, qkvT, bq, bk, bv, 0,
                                             g1, b1, 0, Qh, Kh, Vh, flag);
    for (int l = 0; l < 3; ++l) {
        attn_kernel<<<1024, 256, 0, stream>>>(Qh, Kh, Vh, binsc, kidxg, nkt, tmask,
                                              deF + (long)l * 400, abF + (long)l * 8, att);
        ffglu_kernel<<<512, 256, 0, stream>>>(
            att, oT + (size_t)l * 16384, bo, (long)l * Hq,
            h, g2, b2, (long)l * Hq,
            f1T + (size_t)l * 131072, bf1, (long)l * 1024,
            f2T + (size_t)l * 65536, bf2, (long)l * Hq,
            l == 2 ? d_out : nullptr, flag,
            l < 2 ? qkvT + (size_t)(l + 1) * 49152 : (const u16*)nullptr,
            bq, bk, bv, (long)(l + 1) * Hq,
            g1, b1, (long)(l + 1) * Hq,
            Qh, Kh, Vh);
    }
}

// Round 13
// 346.005 us; speedup vs baseline: 1.2106x; 1.0685x over previous
//
#include <hip/hip_runtime.h>
#include <stdint.h>

#define Bq 32
#define Nq 512
#define Hq 128
#define NHq 8
#define HDq 16
#define Mq (Bq * Nq)   // 16384

typedef unsigned short u16;
typedef __attribute__((ext_vector_type(8))) short short8;
typedef __attribute__((ext_vector_type(8))) _Float16 half8;
typedef __attribute__((ext_vector_type(2))) __fp16 fp16x2;
typedef __attribute__((ext_vector_type(4))) float f32x4;

#define LOG2E 1.4426950408889634f
#define QSCALE 0.36067376022224085f   // 0.25 * log2(e)

// ---------- dtype-flex helpers (flag: 1 = inputs are bf16, 0 = f32) ----------
__device__ __forceinline__ float bf2f(u16 v) {
    return __uint_as_float(((unsigned int)v) << 16);
}
__device__ __forceinline__ float ldin(const void* p, long idx, int bf) {
    if (bf) return bf2f(((const u16*)p)[idx]);
    return ((const float*)p)[idx];
}
__device__ __forceinline__ u16 f2bf(float v) {   // RNE
    unsigned int u = __float_as_uint(v);
    return (u16)((u + 0x7FFFu + ((u >> 16) & 1u)) >> 16);
}
__device__ __forceinline__ u16 f2h(float v) {    // f32 -> f16 bits (RNE)
    _Float16 h = (_Float16)v;
    return *(u16*)&h;
}
__device__ __forceinline__ unsigned pk2h(float a, float b) {  // packed f16 pair bits
    fp16x2 c = __builtin_amdgcn_cvt_pkrtz(a, b);
    return *(unsigned*)&c;
}

// ---------- merged prep: dtype detect + converts + mask bits + kprep ----------
__global__ void prep_kernel(const void* xraw, const void* de, const void* ab,
                            const void* mraw, int* flag, float* deo, float* abo,
                            unsigned* mbits, int n,
                            u16* __restrict__ kidxg, int* __restrict__ nkt,
                            unsigned* __restrict__ tmask) {
    __shared__ int cnt, orA, orB, orC, orD;
    __shared__ unsigned smb[512];
    int tid = threadIdx.x;
    if (tid == 0) { cnt = 0; orA = 0; orB = 0; orC = 0; orD = 0; }
    __syncthreads();
    const u16* u = (const u16*)xraw;
    int good = 0;
    for (int i = tid; i < 1024; i += 256) {
        u16 v = u[i];
        int e = (v >> 7) & 0xFF;
        if (v == 0 || (e >= 90 && e <= 141)) good++;
    }
    atomicAdd(&cnt, good);
    const uint4* p4 = (const uint4*)mraw;
    unsigned a = 0, b = 0, c = 0, d = 0;
    for (int i = tid; i < n / 16; i += 256) {
        uint4 w = p4[i];
        unsigned all = w.x | w.y | w.z | w.w;
        a |= all & 0xFEFEFEFEu;
        b |= all & 0x0000FF00u;
        c |= all & 0xFFFFFF00u;
        d |= w.y | w.w;
    }
    if (a) atomicOr(&orA, 1);
    if (b) atomicOr(&orB, 1);
    if (c) atomicOr(&orC, 1);
    if (d) atomicOr(&orD, 1);
    __syncthreads();
    int bf = (cnt >= 900);
    if (tid == 0) *flag = bf;
    int mode;  // 0 bool8, 1 int32, 2 int64, 3 bf16, 4 f32
    if (orA) mode = orB ? 3 : 4;
    else if (orC) mode = 0;
    else mode = orD ? 1 : 2;
    for (int i = tid; i < 1200; i += 256) deo[i] = ldin(de, i, bf);
    if (tid < 24) abo[tid] = ldin(ab, tid, bf);
    const unsigned char* p = (const unsigned char*)mraw;
    for (int wI = tid; wI < n / 32; wI += 256) {
        unsigned word = 0;
        for (int j = 0; j < 32; ++j) {
            int i = wI * 32 + j;
            int v;
            switch (mode) {
                case 0: v = p[i]; break;
                case 1: v = ((const int*)p)[i]; break;
                case 2: v = (int)((const long long*)p)[i]; break;
                case 3: v = ((const u16*)p)[i] != 0; break;
                default: v = (((const float*)p)[i] != 0.0f); break;
            }
            if (v) word |= 1u << j;
        }
        mbits[wI] = word;
        smb[wI] = word;
    }
    __syncthreads();
    // --- kprep fold: 64-lane groups sweep batches ---
    int lane = tid & 63;
    for (int bb = tid >> 6; bb < 32; bb += 4) {
        int pos_base = 0;
        for (int w = 0; w < 8; ++w) {
            unsigned lo = smb[bb * 16 + 2 * w], hi = smb[bb * 16 + 2 * w + 1];
            unsigned long long word = ((unsigned long long)hi << 32) | lo;
            unsigned long long un = ~word;   // 1 = unmasked
            int bit = (int)((un >> lane) & 1ull);
            unsigned long long before = un & ((1ull << lane) - 1ull);
            int pos = pos_base + __popcll(before);
            if (bit) kidxg[bb * 512 + pos] = (u16)(w * 64 + lane);
            pos_base += __popcll(un);
        }
        int nk = pos_base;
        int nkp = (nk + 31) & ~31;
        if (nkp == 0) nkp = 32;
        int nt = nkp >> 5;
        for (int j = nk + lane; j < nkp; j += 64) kidxg[bb * 512 + j] = 0;
        if (lane == 0) {
            nkt[bb] = nt;
            for (int t = 0; t < 16; ++t) tmask[bb * 16 + t] = 0;
            int rem = nk & 31;
            if (rem) tmask[bb * 16 + nt - 1] = 0xFFFFFFFFu << rem;
            if (nk == 0) tmask[bb * 16] = 0xFFFFFFFFu;
        }
    }
}

// ---------- setup2: binsc + init + wtrans fused (range-switched grid) ------
// [0,2048): binsc. [2048,3072): init copy. [3072,3840): wtrans.
__global__ __launch_bounds__(256) void setup2_kernel(
    const void* __restrict__ dist, const u16* __restrict__ kidxg,
    const int* __restrict__ nktp, unsigned char* __restrict__ binsc,
    const void* x, float* __restrict__ h,
    const void* Wqr, const void* Wkr, const void* Wvr, const void* Wor,
    const void* Wf1r, const void* Wf2r,
    u16* qkvT, u16* oT, u16* f1T, u16* f2T, const int* flagp) {
    __shared__ u16 kl[512];
    __shared__ int ntS;
    __shared__ u16 Ts[32][33];
    int id = blockIdx.x;
    int tid = threadIdx.x;
    int bf = *flagp;
    if (id < 2048) {
        int b = id >> 6;
        int q0 = (id & 63) * 8;
        if (tid == 0) ntS = nktp[b];
        kl[tid] = kidxg[b * 512 + tid];
        kl[tid + 256] = kidxg[b * 512 + tid + 256];
        __syncthreads();
        int nkp = ntS * 32;
        for (int rq = 0; rq < 8; ++rq) {
            int q = q0 + rq;
            long rowoff = ((long)b * 512 + q) * 512;
            for (int j = tid; j < nkp; j += 256) {
                float d = ldin(dist, rowoff + kl[j], bf);
                int v = (int)(d * 10.0f);
                v = v < 0 ? 0 : (v > 49 ? 49 : v);
                binsc[((size_t)b * 512 + q) * 512 + j] = (unsigned char)(v << 2);
            }
        }
    } else if (id < 3072) {
        int i = (id - 2048) * 256 + tid;
        long base = (long)i * 8;
        if (bf) {
            uint4 w = ((const uint4*)x)[i];
            const u16* ws = (const u16*)&w;
            float o[8];
#pragma unroll
            for (int k = 0; k < 8; ++k) o[k] = bf2f(ws[k]);
            *(float4*)&h[base] = *(float4*)&o[0];
            *(float4*)&h[base + 4] = *(float4*)&o[4];
        } else {
            float4 a = ((const float4*)x)[2 * i];
            float4 b2v = ((const float4*)x)[2 * i + 1];
            *(float4*)&h[base] = a;
            *(float4*)&h[base + 4] = b2v;
        }
    } else {
        int bid = id - 3072;
        int l = bid >> 8, r = bid & 255;
        const void* src; u16* dst; long soff, doff; int Kd, Nd, t;
        if (r < 64) {
            int mat = r >> 4; t = r & 15; Kd = 128; Nd = 128;
            soff = (long)l * 16384;
            if (mat == 0)      { src = Wqr; dst = qkvT; doff = (long)l * 49152; }
            else if (mat == 1) { src = Wkr; dst = qkvT; doff = (long)l * 49152 + 16384; }
            else if (mat == 2) { src = Wvr; dst = qkvT; doff = (long)l * 49152 + 32768; }
            else               { src = Wor; dst = oT;   doff = (long)l * 16384; }
        } else if (r < 192) {
            t = r - 64; Kd = 128; Nd = 1024;
            src = Wf1r; soff = (long)l * 131072; dst = f1T; doff = (long)l * 131072;
        } else {
            t = r - 192; Kd = 512; Nd = 128;
            src = Wf2r; soff = (long)l * 65536; dst = f2T; doff = (long)l * 65536;
        }
        int ntile = Nd >> 5;
        int tk = t / ntile, tn = t % ntile;
        int rr = tid >> 3, cc0 = (tid & 7) * 4;
#pragma unroll
        for (int i = 0; i < 4; ++i) {
            long idx = soff + (long)(tk * 32 + rr) * Nd + tn * 32 + cc0 + i;
            Ts[rr][cc0 + i] = f2bf(ldin(src, idx, bf));
        }
        __syncthreads();
#pragma unroll
        for (int i = 0; i < 4; ++i) {
            long idx = doff + (long)(tn * 32 + rr) * Kd + tk * 32 + cc0 + i;
            dst[idx] = Ts[cc0 + i][rr];
        }
    }
}

// ===== QKV (layer 0 only): LN once, Q/K/V looped, B streamed from L2 =====
__global__ __launch_bounds__(256, 4) void qkv_mfma_kernel(
    const float* __restrict__ h, const u16* __restrict__ qkvT_l,
    const void* bqr, const void* bkr, const void* bvr, long bOff,
    const void* g1raw, const void* b1raw, long lnOff,
    u16* __restrict__ Qo, u16* __restrict__ Ko, u16* __restrict__ Vo,
    const int* flagp) {
    __shared__ __align__(16) u16 As[32][136];
    int tid = threadIdx.x;
    int m0 = blockIdx.x * 32;
    int bf = *flagp;
    {
        int row = tid >> 3, c0 = (tid & 7) * 16;
        const float* hp = h + (size_t)(m0 + row) * 128 + c0;
        float4 f0 = *(const float4*)(hp);
        float4 f1 = *(const float4*)(hp + 4);
        float4 f2 = *(const float4*)(hp + 8);
        float4 f3 = *(const float4*)(hp + 12);
        float vv[16] = {f0.x, f0.y, f0.z, f0.w, f1.x, f1.y, f1.z, f1.w,
                        f2.x, f2.y, f2.z, f2.w, f3.x, f3.y, f3.z, f3.w};
        float s = 0.f, s2 = 0.f;
#pragma unroll
        for (int k = 0; k < 16; ++k) { s += vv[k]; s2 += vv[k] * vv[k]; }
#pragma unroll
        for (int o = 1; o < 8; o <<= 1) {
            s += __shfl_xor(s, o);
            s2 += __shfl_xor(s2, o);
        }
        float mu = s * (1.0f / 128.0f);
        float var = fmaxf(s2 * (1.0f / 128.0f) - mu * mu, 0.0f);
        float rstd = rsqrtf(var + 1e-5f);
        u16 tmp[16];
#pragma unroll
        for (int k = 0; k < 16; ++k) {
            float g = ldin(g1raw, lnOff + c0 + k, bf);
            float b = ldin(b1raw, lnOff + c0 + k, bf);
            tmp[k] = f2bf((vv[k] - mu) * rstd * g + b);
        }
        *(uint4*)&As[row][c0]     = *(uint4*)&tmp[0];
        *(uint4*)&As[row][c0 + 8] = *(uint4*)&tmp[8];
    }
    __syncthreads();
    int wave = tid >> 6, lane = tid & 63;
    int q = lane >> 4, ln = lane & 15;
    int nb = wave * 32;
    f32x4 zero = {0.f, 0.f, 0.f, 0.f};
#pragma unroll
    for (int mat = 0; mat < 3; ++mat) {
        const u16* WT = qkvT_l + (size_t)mat * 16384;
        const void* braw = mat == 0 ? bqr : (mat == 1 ? bkr : bvr);
        u16* C = mat == 0 ? Qo : (mat == 1 ? Ko : Vo);
        float scale = mat == 0 ? QSCALE : 1.0f;
        short8 bfr[2][4];
#pragma unroll
        for (int t = 0; t < 2; ++t)
#pragma unroll
            for (int k4 = 0; k4 < 4; ++k4)
                bfr[t][k4] = *(const short8*)(WT + (size_t)(nb + t * 16 + ln) * 128
                                              + k4 * 32 + q * 8);
        f32x4 acc[2][2];
#pragma unroll
        for (int i = 0; i < 2; ++i)
#pragma unroll
            for (int j = 0; j < 2; ++j) acc[i][j] = zero;
#pragma unroll
        for (int k4 = 0; k4 < 4; ++k4) {
            short8 af0 = *(const short8*)&As[ln][k4 * 32 + q * 8];
            short8 af1 = *(const short8*)&As[16 + ln][k4 * 32 + q * 8];
#pragma unroll
            for (int t = 0; t < 2; ++t) {
                acc[0][t] = __builtin_amdgcn_mfma_f32_16x16x32_bf16(
                    af0, bfr[t][k4], acc[0][t], 0, 0, 0);
                acc[1][t] = __builtin_amdgcn_mfma_f32_16x16x32_bf16(
                    af1, bfr[t][k4], acc[1][t], 0, 0, 0);
            }
        }
#pragma unroll
        for (int t = 0; t < 2; ++t) {
            int n = nb + t * 16 + ln;
            float bias = ldin(braw, bOff + n, bf);
#pragma unroll
            for (int mi = 0; mi < 2; ++mi)
#pragma unroll
                for (int r = 0; r < 4; ++r) {
                    int m = m0 + mi * 16 + q * 4 + r;
                    C[(size_t)m * 128 + n] = f2h((acc[mi][t][r] + bias) * scale);
                }
        }
    }
}

// ===== fused FFN v7: round-10 structure + software-pipelined weight =====
// streams (register double-buffering, fully unrolled chunk loops) and
// entry-issued h-residual loads. 32-row tiles, grid 512, 6 barriers.
__global__ __launch_bounds__(256, 3) void ffglu_kernel(
    const u16* __restrict__ att, const u16* __restrict__ oT_l,
    const void* __restrict__ bo, long boOff, float* __restrict__ h,
    const void* g2, const void* b2, long ln2Off,
    const u16* __restrict__ f1T_l, const void* __restrict__ bf1r, long bf1Off,
    const u16* __restrict__ f2T_l, const void* __restrict__ bf2r, long bf2Off,
    void* __restrict__ outp, const int* flagp,
    const u16* __restrict__ qkvTn,    // next layer qkvT (or nullptr)
    const void* bqr, const void* bkr, const void* bvr, long bOffN,
    const void* g1, const void* b1, long ln1OffN,
    u16* __restrict__ Qo, u16* __restrict__ Ko, u16* __restrict__ Vo) {
    __shared__ __align__(16) u16 As[32][136];   // att stage / hn2 / hn1-next
    __shared__ __align__(16) u16 vg[32][520];   // GLU output (never to HBM)
    __shared__ float stats[32][4][2];
    int tid = threadIdx.x;
    int m0 = blockIdx.x * 32;
    int wave = tid >> 6, lane = tid & 63;
    int q = lane >> 4, ln = lane & 15;
    int nb = wave * 32;
    int bf = *flagp;
    f32x4 zero = {0.f, 0.f, 0.f, 0.f};

    // ---- entry: issue h-residual loads + o-proj B loads + att staging ----
    float hres[2][2][4];
#pragma unroll
    for (int t = 0; t < 2; ++t)
#pragma unroll
        for (int mi = 0; mi < 2; ++mi)
#pragma unroll
            for (int r = 0; r < 4; ++r)
                hres[t][mi][r] = h[(size_t)(m0 + mi * 16 + q * 4 + r) * 128
                                   + nb + t * 16 + ln];
    short8 ob[2][4];
#pragma unroll
    for (int t = 0; t < 2; ++t)
#pragma unroll
        for (int k4 = 0; k4 < 4; ++k4)
            ob[t][k4] = *(const short8*)(oT_l + (size_t)(nb + t * 16 + ln) * 128
                                         + k4 * 32 + q * 8);
#pragma unroll
    for (int i = 0; i < 2; ++i) {
        int idx = tid + i * 256; int r = idx >> 4, c = (idx & 15) << 3;
        *(uint4*)&As[r][c] = *(const uint4*)(att + (size_t)(m0 + r) * 128 + c);
    }
    __syncthreads();                                   // B1
    // ---- o-proj MFMA ----
    f32x4 acc[2][2];
#pragma unroll
    for (int i = 0; i < 2; ++i)
#pragma unroll
        for (int j = 0; j < 2; ++j) acc[i][j] = zero;
#pragma unroll
    for (int k4 = 0; k4 < 4; ++k4) {
        short8 af0 = *(const short8*)&As[ln][k4 * 32 + q * 8];
        short8 af1 = *(const short8*)&As[16 + ln][k4 * 32 + q * 8];
#pragma unroll
        for (int t = 0; t < 2; ++t) {
            acc[0][t] = __builtin_amdgcn_mfma_f32_16x16x32_bf16(
                af0, ob[t][k4], acc[0][t], 0, 0, 0);
            acc[1][t] = __builtin_amdgcn_mfma_f32_16x16x32_bf16(
                af1, ob[t][k4], acc[1][t], 0, 0, 0);
        }
    }
    // ---- epilogue: +bias +resid(hres) -> h1 regs; LN2 partial stats ----
    float h1[2][2][4];
    float srow[2][4], s2row[2][4];
#pragma unroll
    for (int mi = 0; mi < 2; ++mi)
#pragma unroll
        for (int r = 0; r < 4; ++r) { srow[mi][r] = 0.f; s2row[mi][r] = 0.f; }
#pragma unroll
    for (int t = 0; t < 2; ++t) {
        int n = nb + t * 16 + ln;
        float bias = ldin(bo, boOff + n, bf);
#pragma unroll
        for (int mi = 0; mi < 2; ++mi)
#pragma unroll
            for (int r = 0; r < 4; ++r) {
                float v = acc[mi][t][r] + bias + hres[t][mi][r];
                h1[mi][t][r] = v;
                srow[mi][r] += v; s2row[mi][r] += v * v;
            }
    }
#pragma unroll
    for (int mi = 0; mi < 2; ++mi)
#pragma unroll
        for (int r = 0; r < 4; ++r)
#pragma unroll
            for (int o = 1; o < 16; o <<= 1) {
                srow[mi][r] += __shfl_xor(srow[mi][r], o);
                s2row[mi][r] += __shfl_xor(s2row[mi][r], o);
            }
    if (ln == 0) {
#pragma unroll
        for (int mi = 0; mi < 2; ++mi)
#pragma unroll
            for (int r = 0; r < 4; ++r) {
                stats[mi * 16 + q * 4 + r][wave][0] = srow[mi][r];
                stats[mi * 16 + q * 4 + r][wave][1] = s2row[mi][r];
            }
    }
    __syncthreads();                                   // B2
    // ---- LN2 -> hn2 (As overlay) ----
    float mu[2][4], rs[2][4];
#pragma unroll
    for (int mi = 0; mi < 2; ++mi)
#pragma unroll
        for (int r = 0; r < 4; ++r) {
            int row = mi * 16 + q * 4 + r;
            float s = (stats[row][0][0] + stats[row][1][0]) +
                      (stats[row][2][0] + stats[row][3][0]);
            float s2 = (stats[row][0][1] + stats[row][1][1]) +
                       (stats[row][2][1] + stats[row][3][1]);
            mu[mi][r] = s * (1.0f / 128.0f);
            float var = fmaxf(s2 * (1.0f / 128.0f) - mu[mi][r] * mu[mi][r], 0.0f);
            rs[mi][r] = rsqrtf(var + 1e-5f);
        }
#pragma unroll
    for (int t = 0; t < 2; ++t) {
        int n = nb + t * 16 + ln;
        float g = ldin(g2, ln2Off + n, bf), bb = ldin(b2, ln2Off + n, bf);
#pragma unroll
        for (int mi = 0; mi < 2; ++mi)
#pragma unroll
            for (int r = 0; r < 4; ++r)
                As[mi * 16 + q * 4 + r][n] =
                    f2bf((h1[mi][t][r] - mu[mi][r]) * rs[mi][r] * g + bb);
    }
    __syncthreads();                                   // B3
    // ---- ff1: 8 chunks of 64 GLU cols, pipelined weight loads ----
    int nb16 = wave * 16;
    short8 ba[4], bb8[4], ban[4], bbn[4];
#pragma unroll
    for (int k4 = 0; k4 < 4; ++k4) {
        ba[k4]  = *(const short8*)(f1T_l + (size_t)(nb16 + ln) * 128
                                   + k4 * 32 + q * 8);
        bb8[k4] = *(const short8*)(f1T_l + (size_t)(512 + nb16 + ln) * 128
                                   + k4 * 32 + q * 8);
    }
#pragma unroll
    for (int ch = 0; ch < 8; ++ch) {
        if (ch < 7) {
            int arow = (ch + 1) * 64 + nb16;
#pragma unroll
            for (int k4 = 0; k4 < 4; ++k4) {
                ban[k4] = *(const short8*)(f1T_l + (size_t)(arow + ln) * 128
                                           + k4 * 32 + q * 8);
                bbn[k4] = *(const short8*)(f1T_l + (size_t)(512 + arow + ln) * 128
                                           + k4 * 32 + q * 8);
            }
        }
        f32x4 aA[2] = {zero, zero}, aB[2] = {zero, zero};
#pragma unroll
        for (int k4 = 0; k4 < 4; ++k4) {
            short8 af0 = *(const short8*)&As[ln][k4 * 32 + q * 8];
            short8 af1 = *(const short8*)&As[16 + ln][k4 * 32 + q * 8];
            aA[0] = __builtin_amdgcn_mfma_f32_16x16x32_bf16(af0, ba[k4], aA[0], 0, 0, 0);
            aA[1] = __builtin_amdgcn_mfma_f32_16x16x32_bf16(af1, ba[k4], aA[1], 0, 0, 0);
            aB[0] = __builtin_amdgcn_mfma_f32_16x16x32_bf16(af0, bb8[k4], aB[0], 0, 0, 0);
            aB[1] = __builtin_amdgcn_mfma_f32_16x16x32_bf16(af1, bb8[k4], aB[1], 0, 0, 0);
        }
        int n = ch * 64 + nb16 + ln;
        float bA = ldin(bf1r, bf1Off + n, bf);
        float bB = ldin(bf1r, bf1Off + 512 + n, bf);
#pragma unroll
        for (int mi = 0; mi < 2; ++mi)
#pragma unroll
            for (int r = 0; r < 4; ++r) {
                float ua = aA[mi][r] + bA, ub = aB[mi][r] + bB;
                vg[mi * 16 + q * 4 + r][n] = f2bf(ua / (1.0f + __expf(-ub)));
            }
        if (ch < 7) {
#pragma unroll
            for (int k4 = 0; k4 < 4; ++k4) { ba[k4] = ban[k4]; bb8[k4] = bbn[k4]; }
        }
    }
    __syncthreads();                                   // B4
    // ---- ff2: K=512 in 4 chunks, pipelined weight loads ----
    f32x4 accF[2][2];
#pragma unroll
    for (int i = 0; i < 2; ++i)
#pragma unroll
        for (int j = 0; j < 2; ++j) accF[i][j] = zero;
    short8 fb[2][4], fbn[2][4];
#pragma unroll
    for (int t = 0; t < 2; ++t)
#pragma unroll
        for (int k4 = 0; k4 < 4; ++k4)
            fb[t][k4] = *(const short8*)(f2T_l + (size_t)(nb + t * 16 + ln) * 512
                                         + k4 * 32 + q * 8);
#pragma unroll
    for (int fc = 0; fc < 4; ++fc) {
        if (fc < 3) {
            int k0 = (fc + 1) * 128;
#pragma unroll
            for (int t = 0; t < 2; ++t)
#pragma unroll
                for (int k4 = 0; k4 < 4; ++k4)
                    fbn[t][k4] = *(const short8*)(f2T_l
                                  + (size_t)(nb + t * 16 + ln) * 512
                                  + k0 + k4 * 32 + q * 8);
        }
#pragma unroll
        for (int k4 = 0; k4 < 4; ++k4) {
            short8 af0 = *(const short8*)&vg[ln][fc * 128 + k4 * 32 + q * 8];
            short8 af1 = *(const short8*)&vg[16 + ln][fc * 128 + k4 * 32 + q * 8];
#pragma unroll
            for (int t = 0; t < 2; ++t) {
                accF[0][t] = __builtin_amdgcn_mfma_f32_16x16x32_bf16(
                    af0, fb[t][k4], accF[0][t], 0, 0, 0);
                accF[1][t] = __builtin_amdgcn_mfma_f32_16x16x32_bf16(
                    af1, fb[t][k4], accF[1][t], 0, 0, 0);
            }
        }
        if (fc < 3) {
#pragma unroll
            for (int t = 0; t < 2; ++t)
#pragma unroll
                for (int k4 = 0; k4 < 4; ++k4) fb[t][k4] = fbn[t][k4];
        }
    }
    // ---- epilogue: +bias +resid -> h (and h1 regs for next-layer LN1) ----
#pragma unroll
    for (int t = 0; t < 2; ++t) {
        int n = nb + t * 16 + ln;
        float bias = ldin(bf2r, bf2Off + n, bf);
#pragma unroll
        for (int mi = 0; mi < 2; ++mi)
#pragma unroll
            for (int r = 0; r < 4; ++r) {
                int m = m0 + mi * 16 + q * 4 + r;
                float v = accF[mi][t][r] + bias + h1[mi][t][r];
                h[(size_t)m * 128 + n] = v;
                h1[mi][t][r] = v;   // reuse for LN1-next
                if (outp) {
                    if (bf) ((u16*)outp)[(size_t)m * 128 + n] = f2bf(v);
                    else ((float*)outp)[(size_t)m * 128 + n] = v;
                }
            }
    }
    if (!qkvTn) return;
    // ---- LN1 (next layer) stats ----
#pragma unroll
    for (int mi = 0; mi < 2; ++mi)
#pragma unroll
        for (int r = 0; r < 4; ++r) { srow[mi][r] = 0.f; s2row[mi][r] = 0.f; }
#pragma unroll
    for (int t = 0; t < 2; ++t)
#pragma unroll
        for (int mi = 0; mi < 2; ++mi)
#pragma unroll
            for (int r = 0; r < 4; ++r) {
                float v = h1[mi][t][r];
                srow[mi][r] += v; s2row[mi][r] += v * v;
            }
#pragma unroll
    for (int mi = 0; mi < 2; ++mi)
#pragma unroll
        for (int r = 0; r < 4; ++r)
#pragma unroll
            for (int o = 1; o < 16; o <<= 1) {
                srow[mi][r] += __shfl_xor(srow[mi][r], o);
                s2row[mi][r] += __shfl_xor(s2row[mi][r], o);
            }
    if (ln == 0) {
#pragma unroll
        for (int mi = 0; mi < 2; ++mi)
#pragma unroll
            for (int r = 0; r < 4; ++r) {
                stats[mi * 16 + q * 4 + r][wave][0] = srow[mi][r];
                stats[mi * 16 + q * 4 + r][wave][1] = s2row[mi][r];
            }
    }
    __syncthreads();                                   // B5
#pragma unroll
    for (int mi = 0; mi < 2; ++mi)
#pragma unroll
        for (int r = 0; r < 4; ++r) {
            int row = mi * 16 + q * 4 + r;
            float s = (stats[row][0][0] + stats[row][1][0]) +
                      (stats[row][2][0] + stats[row][3][0]);
            float s2 = (stats[row][0][1] + stats[row][1][1]) +
                       (stats[row][2][1] + stats[row][3][1]);
            mu[mi][r] = s * (1.0f / 128.0f);
            float var = fmaxf(s2 * (1.0f / 128.0f) - mu[mi][r] * mu[mi][r], 0.0f);
            rs[mi][r] = rsqrtf(var + 1e-5f);
        }
#pragma unroll
    for (int t = 0; t < 2; ++t) {
        int n = nb + t * 16 + ln;
        float g = ldin(g1, ln1OffN + n, bf), bb = ldin(b1, ln1OffN + n, bf);
#pragma unroll
        for (int mi = 0; mi < 2; ++mi)
#pragma unroll
            for (int r = 0; r < 4; ++r)
                As[mi * 16 + q * 4 + r][n] =
                    f2bf((h1[mi][t][r] - mu[mi][r]) * rs[mi][r] * g + bb);
    }
    __syncthreads();                                   // B6
    // ---- next-layer QKV: B streamed, pipelined across mats ----
    short8 qb[2][4], qbn[2][4];
#pragma unroll
    for (int t = 0; t < 2; ++t)
#pragma unroll
        for (int k4 = 0; k4 < 4; ++k4)
            qb[t][k4] = *(const short8*)(qkvTn + (size_t)(nb + t * 16 + ln) * 128
                                         + k4 * 32 + q * 8);
#pragma unroll
    for (int mat = 0; mat < 3; ++mat) {
        if (mat < 2) {
            const u16* WTn = qkvTn + (size_t)(mat + 1) * 16384;
#pragma unroll
            for (int t = 0; t < 2; ++t)
#pragma unroll
                for (int k4 = 0; k4 < 4; ++k4)
                    qbn[t][k4] = *(const short8*)(WTn
                                  + (size_t)(nb + t * 16 + ln) * 128
                                  + k4 * 32 + q * 8);
        }
        const void* braw = mat == 0 ? bqr : (mat == 1 ? bkr : bvr);
        u16* C = mat == 0 ? Qo : (mat == 1 ? Ko : Vo);
        float scale = mat == 0 ? QSCALE : 1.0f;
        f32x4 aq[2][2];
#pragma unroll
        for (int i = 0; i < 2; ++i)
#pragma unroll
            for (int j = 0; j < 2; ++j) aq[i][j] = zero;
#pragma unroll
        for (int k4 = 0; k4 < 4; ++k4) {
            short8 af0 = *(const short8*)&As[ln][k4 * 32 + q * 8];
            short8 af1 = *(const short8*)&As[16 + ln][k4 * 32 + q * 8];
#pragma unroll
            for (int t = 0; t < 2; ++t) {
                aq[0][t] = __builtin_amdgcn_mfma_f32_16x16x32_bf16(
                    af0, qb[t][k4], aq[0][t], 0, 0, 0);
                aq[1][t] = __builtin_amdgcn_mfma_f32_16x16x32_bf16(
                    af1, qb[t][k4], aq[1][t], 0, 0, 0);
            }
        }
#pragma unroll
        for (int t = 0; t < 2; ++t) {
            int n = nb + t * 16 + ln;
            float bias = ldin(braw, bOffN + n, bf);
#pragma unroll
            for (int mi = 0; mi < 2; ++mi)
#pragma unroll
                for (int r = 0; r < 4; ++r) {
                    int m = m0 + mi * 16 + q * 4 + r;
                    C[(size_t)m * 128 + n] = f2h((aq[mi][t][r] + bias) * scale);
                }
        }
        if (mat < 2) {
#pragma unroll
            for (int t = 0; t < 2; ++t)
#pragma unroll
                for (int k4 = 0; k4 < 4; ++k4) qb[t][k4] = qbn[t][k4];
        }
    }
}

// ========== attention v6: exp2-domain softmax (Q pre-scaled by log2e) =======
__global__ __launch_bounds__(256, 4) void attn_kernel(
    const u16* __restrict__ Qh, const u16* __restrict__ Kh,
    const u16* __restrict__ Vh, const unsigned char* __restrict__ binsc,
    const u16* __restrict__ kidxg, const int* __restrict__ nktp,
    const unsigned* __restrict__ tmaskp, const float* __restrict__ deL,
    const float* __restrict__ abL, u16* __restrict__ out) {
    // de-swizzle: heads of one (b,qq) share id%8 -> same XCD L2 for binsc
    int id = blockIdx.x;
    int c = id & 7, t5 = id >> 3;
    int nh = t5 & 7;
    int pair = ((t5 >> 3) << 3) | c;
    int b = pair >> 2, qq = pair & 3;

    __shared__ __align__(16) u16 KsF[8192];      // frag-major K, 16 KB
    __shared__ __align__(16) u16 VT[16 * 520];   // V^T rows 520 f16, 16.25 KB
    __shared__ __align__(16) u16 Pl[4 * 16 * 40];// per-wave P tile, 5 KB

    int tid = threadIdx.x;
    int nt = __builtin_amdgcn_readfirstlane(nktp[b]);
    int nkp = nt * 32;
    const u16* Kp = Kh + (size_t)(b * Nq) * Hq + nh * HDq;
    const u16* Vp = Vh + (size_t)(b * Nq) * Hq + nh * HDq;
    for (int r = tid; r < nkp; r += 256) {
        int row = kidxg[b * 512 + r];
        int kt = r >> 5, s = (r >> 4) & 1, lnr = r & 15;
        uint4 k0v = *(const uint4*)(Kp + (size_t)row * Hq);
        uint4 k1v = *(const uint4*)(Kp + (size_t)row * Hq + 8);
        *(uint4*)&KsF[kt * 512 + s * 256 + lnr * 8]       = k0v;  // d 0..7
        *(uint4*)&KsF[kt * 512 + s * 256 + 128 + lnr * 8] = k1v;  // d 8..15
        uint4 v0 = *(const uint4*)(Vp + (size_t)row * Hq);
        uint4 v1 = *(const uint4*)(Vp + (size_t)row * Hq + 8);
        u16 vv[16];
        *(uint4*)&vv[0] = v0; *(uint4*)&vv[8] = v1;
#pragma unroll
        for (int d = 0; d < 16; ++d) VT[d * 520 + r] = vv[d];
    }
    __syncthreads();

    int wave = tid >> 6, lane = tid & 63;
    int quad = lane >> 4, ln = lane & 15;
    int q0w = qq * 128 + wave * 32;

    float tblf = (lane < 50) ? (deL[lane * NHq + nh] + abL[nh]) * LOG2E : 0.0f;
    int tbli = __float_as_int(tblf);
    unsigned tl = tmaskp[b * 16 + nt - 1];

    // hoisted Q B-frags (quads 2,3 supply the zero d-padding)
    half8 qf[2];
#pragma unroll
    for (int t = 0; t < 2; ++t) {
        uint4 qv = {0, 0, 0, 0};
        if (quad < 2)
            qv = *(const uint4*)(Qh + (size_t)(b * Nq + q0w + t * 16 + ln) * Hq
                                 + nh * HDq + quad * 8);
        qf[t] = *(half8*)&qv;
    }

    f32x4 zero = {0.f, 0.f, 0.f, 0.f};
    f32x4 acc[2] = {zero, zero};
    float zp[2] = {0.f, 0.f};
    _Float16* Pw = (_Float16*)&Pl[wave * 640];
    const _Float16* KsH = (const _Float16*)KsF;
    const _Float16* VTH = (const _Float16*)VT;
    const unsigned char* brow0 = binsc + ((size_t)b * 512 + (q0w + ln)) * 512;
    const unsigned char* brow1 = brow0 + (size_t)16 * 512;

    // prefetch kt=0 bias-byte dwords
    unsigned pb00 = *(const unsigned*)(brow0 + quad * 4);
    unsigned pb01 = *(const unsigned*)(brow0 + 16 + quad * 4);
    unsigned pb10 = *(const unsigned*)(brow1 + quad * 4);
    unsigned pb11 = *(const unsigned*)(brow1 + 16 + quad * 4);

    for (int kt = 0; kt < nt; ++kt) {
        int k0 = kt * 32;
        unsigned w = (kt == nt - 1) ? tl : 0u;
        unsigned cb00 = pb00, cb01 = pb01, cb10 = pb10, cb11 = pb11;
        if (kt < nt - 1) {
            pb00 = *(const unsigned*)(brow0 + k0 + 32 + quad * 4);
            pb01 = *(const unsigned*)(brow0 + k0 + 48 + quad * 4);
            pb10 = *(const unsigned*)(brow1 + k0 + 32 + quad * 4);
            pb11 = *(const unsigned*)(brow1 + k0 + 48 + quad * 4);
        }
        half8 vb = *(const half8*)(VTH + ln * 520 + k0 + quad * 8);
        half8 ka0 = {}, ka1 = {};
        if (quad < 2) {
            ka0 = *(const half8*)(KsH + kt * 512 + quad * 128 + ln * 8);
            ka1 = *(const half8*)(KsH + kt * 512 + 256 + quad * 128 + ln * 8);
        }
#pragma unroll
        for (int t = 0; t < 2; ++t) {
            unsigned bw0 = t == 0 ? cb00 : cb10;
            unsigned bw1 = t == 0 ? cb01 : cb11;
            f32x4 s0 = __builtin_amdgcn_mfma_f32_16x16x32_f16(ka0, qf[t], zero, 0, 0, 0);
            f32x4 s1 = __builtin_amdgcn_mfma_f32_16x16x32_f16(ka1, qf[t], zero, 0, 0, 0);
            float p[8];
#pragma unroll
            for (int r = 0; r < 4; ++r) {
                float bias = __int_as_float(__builtin_amdgcn_ds_bpermute(
                    (int)((bw0 >> (8 * r)) & 0xFFu), tbli));
                float sc = s0[r] + bias;
                bool m = (w >> (quad * 4 + r)) & 1u;
                p[r] = m ? 0.0f : __builtin_amdgcn_exp2f(sc);
            }
#pragma unroll
            for (int r = 0; r < 4; ++r) {
                float bias = __int_as_float(__builtin_amdgcn_ds_bpermute(
                    (int)((bw1 >> (8 * r)) & 0xFFu), tbli));
                float sc = s1[r] + bias;
                bool m = (w >> (16 + quad * 4 + r)) & 1u;
                p[4 + r] = m ? 0.0f : __builtin_amdgcn_exp2f(sc);
            }
            zp[t] += ((p[0] + p[1]) + (p[2] + p[3])) +
                     ((p[4] + p[5]) + (p[6] + p[7]));
            uint2 w0, w1;
            w0.x = pk2h(p[0], p[1]); w0.y = pk2h(p[2], p[3]);
            w1.x = pk2h(p[4], p[5]); w1.y = pk2h(p[6], p[7]);
            *(uint2*)(Pw + ln * 40 + quad * 4)      = w0;   // k = quad*4+r
            *(uint2*)(Pw + ln * 40 + 16 + quad * 4) = w1;   // k = 16+quad*4+r
            half8 pa = *(const half8*)(Pw + ln * 40 + quad * 8); // A[m=ln][k=quad*8+j]
            acc[t] = __builtin_amdgcn_mfma_f32_16x16x32_f16(pa, vb, acc[t], 0, 0, 0);
        }
    }
#pragma unroll
    for (int t = 0; t < 2; ++t) {
        zp[t] += __shfl_xor(zp[t], 16);
        zp[t] += __shfl_xor(zp[t], 32);
    }
#pragma unroll
    for (int t = 0; t < 2; ++t) {
#pragma unroll
        for (int r = 0; r < 4; ++r) {
            float zz = __shfl(zp[t], quad * 4 + r);
            float val = acc[t][r] / fmaxf(zz, 1e-35f);
            int qrow = q0w + t * 16 + quad * 4 + r;
            out[(size_t)(b * Nq + qrow) * Hq + nh * HDq + ln] = f2bf(val);
        }
    }
}

extern "C" void kernel_launch(void* const* d_in, const int* in_sizes, int n_in,
                              void* d_out, int out_size, void* d_ws, size_t ws_size,
                              hipStream_t stream) {
    const void* x  = d_in[0];
    const void* dist = d_in[1];
    const void* mask = d_in[2];
    const void* Wq = d_in[3];  const void* bq = d_in[4];
    const void* Wk = d_in[5];  const void* bk = d_in[6];
    const void* Wv = d_in[7];  const void* bv = d_in[8];
    const void* Wo = d_in[9];  const void* bo = d_in[10];
    const void* de = d_in[11]; const void* ab = d_in[12];
    const void* g1 = d_in[13]; const void* b1 = d_in[14];
    const void* g2 = d_in[15]; const void* b2 = d_in[16];
    const void* Wf1 = d_in[17]; const void* bf1 = d_in[18];
    const void* Wf2 = d_in[19]; const void* bf2 = d_in[20];

    char* ws = (char*)d_ws;
    const size_t OFF_DE   = 64;
    const size_t OFF_AB   = 5120;
    const size_t OFF_BINS = 8192;                    // binsc 8,388,608
    const size_t OFF_MSK  = OFF_BINS + 8388608;      // mbits 2 KB (4096 res)
    const size_t OFF_KIDX = OFF_MSK + 4096;          // 32768
    const size_t OFF_NKT  = OFF_KIDX + 32768;        // 256
    const size_t OFF_TM   = OFF_NKT + 256;           // 2048
    const size_t OFF_H    = OFF_TM + 4096;           // f32 8,388,608
    const size_t OFF_QKV  = OFF_H + 8388608;         // Qh,Kh,Vh f16
    const size_t OFF_ATT  = OFF_QKV + 25165824;      // u16 4,194,304
    const size_t OFF_WT   = OFF_ATT + 4194304;       // u16 1,572,864
    const size_t NEEDED   = OFF_WT + 1572864;
    if (ws_size < NEEDED) return;

    int* flag = (int*)ws;
    float* deF = (float*)(ws + OFF_DE);
    float* abF = (float*)(ws + OFF_AB);
    unsigned char* binsc = (unsigned char*)(ws + OFF_BINS);
    unsigned* mbits = (unsigned*)(ws + OFF_MSK);
    u16* kidxg = (u16*)(ws + OFF_KIDX);
    int* nkt = (int*)(ws + OFF_NKT);
    unsigned* tmask = (unsigned*)(ws + OFF_TM);
    float* h = (float*)(ws + OFF_H);
    u16* Qh = (u16*)(ws + OFF_QKV);
    u16* Kh = Qh + 2097152;
    u16* Vh = Qh + 2 * 2097152;
    u16* att = (u16*)(ws + OFF_ATT);
    u16* qkvT = (u16*)(ws + OFF_WT);
    u16* oT  = qkvT + 147456;
    u16* f1T = oT + 49152;
    u16* f2T = f1T + 393216;

    prep_kernel<<<1, 256, 0, stream>>>(x, de, ab, mask, flag, deF, abF, mbits,
                                       Bq * Nq, kidxg, nkt, tmask);
    setup2_kernel<<<3840, 256, 0, stream>>>(dist, kidxg, nkt, binsc, x, h,
                                            Wq, Wk, Wv, Wo, Wf1, Wf2,
                                            qkvT, oT, f1T, f2T, flag);
    qkv_mfma_kernel<<<512, 256, 0, stream>>>(h, qkvT, bq, bk, bv, 0,
                                             g1, b1, 0, Qh, Kh, Vh, flag);
    for (int l = 0; l < 3; ++l) {
        attn_kernel<<<1024, 256, 0, stream>>>(Qh, Kh, Vh, binsc, kidxg, nkt, tmask,
                                              deF + (long)l * 400, abF + (long)l * 8, att);
        ffglu_kernel<<<512, 256, 0, stream>>>(
            att, oT + (size_t)l * 16384, bo, (long)l * Hq,
            h, g2, b2, (long)l * Hq,
            f1T + (size_t)l * 131072, bf1, (long)l * 1024,
            f2T + (size_t)l * 65536, bf2, (long)l * Hq,
            l == 2 ? d_out : nullptr, flag,
            l < 2 ? qkvT + (size_t)(l + 1) * 49152 : (const u16*)nullptr,
            bq, bk, bv, (long)(l + 1) * Hq,
            g1, b1, (long)(l + 1) * Hq,
            Qh, Kh, Vh);
    }
}

// Round 14
// 345.013 us; speedup vs baseline: 1.2141x; 1.0029x over previous
//
#include <hip/hip_runtime.h>
#include <stdint.h>

#define Bq 32
#define Nq 512
#define Hq 128
#define NHq 8
#define HDq 16
#define Mq (Bq * Nq)   // 16384

typedef unsigned short u16;
typedef __attribute__((ext_vector_type(8))) short short8;
typedef __attribute__((ext_vector_type(8))) _Float16 half8;
typedef __attribute__((ext_vector_type(2))) __fp16 fp16x2;
typedef __attribute__((ext_vector_type(4))) float f32x4;

#define LOG2E 1.4426950408889634f
#define QSCALE 0.36067376022224085f   // 0.25 * log2(e)

// ---------- dtype-flex helpers (flag: 1 = inputs are bf16, 0 = f32) ----------
__device__ __forceinline__ float bf2f(u16 v) {
    return __uint_as_float(((unsigned int)v) << 16);
}
__device__ __forceinline__ float ldin(const void* p, long idx, int bf) {
    if (bf) return bf2f(((const u16*)p)[idx]);
    return ((const float*)p)[idx];
}
__device__ __forceinline__ u16 f2bf(float v) {   // RNE
    unsigned int u = __float_as_uint(v);
    return (u16)((u + 0x7FFFu + ((u >> 16) & 1u)) >> 16);
}
__device__ __forceinline__ u16 f2h(float v) {    // f32 -> f16 bits (RNE)
    _Float16 h = (_Float16)v;
    return *(u16*)&h;
}
__device__ __forceinline__ unsigned pk2h(float a, float b) {  // packed f16 pair bits
    fp16x2 c = __builtin_amdgcn_cvt_pkrtz(a, b);
    return *(unsigned*)&c;
}

// ---------- merged prep: dtype detect + converts + mask bits + kprep ----------
__global__ void prep_kernel(const void* xraw, const void* de, const void* ab,
                            const void* mraw, int* flag, float* deo, float* abo,
                            unsigned* mbits, int n,
                            u16* __restrict__ kidxg, int* __restrict__ nkt,
                            unsigned* __restrict__ tmask) {
    __shared__ int cnt, orA, orB, orC, orD;
    __shared__ unsigned smb[512];
    int tid = threadIdx.x;
    if (tid == 0) { cnt = 0; orA = 0; orB = 0; orC = 0; orD = 0; }
    __syncthreads();
    const u16* u = (const u16*)xraw;
    int good = 0;
    for (int i = tid; i < 1024; i += 256) {
        u16 v = u[i];
        int e = (v >> 7) & 0xFF;
        if (v == 0 || (e >= 90 && e <= 141)) good++;
    }
    atomicAdd(&cnt, good);
    const uint4* p4 = (const uint4*)mraw;
    unsigned a = 0, b = 0, c = 0, d = 0;
    for (int i = tid; i < n / 16; i += 256) {
        uint4 w = p4[i];
        unsigned all = w.x | w.y | w.z | w.w;
        a |= all & 0xFEFEFEFEu;
        b |= all & 0x0000FF00u;
        c |= all & 0xFFFFFF00u;
        d |= w.y | w.w;
    }
    if (a) atomicOr(&orA, 1);
    if (b) atomicOr(&orB, 1);
    if (c) atomicOr(&orC, 1);
    if (d) atomicOr(&orD, 1);
    __syncthreads();
    int bf = (cnt >= 900);
    if (tid == 0) *flag = bf;
    int mode;  // 0 bool8, 1 int32, 2 int64, 3 bf16, 4 f32
    if (orA) mode = orB ? 3 : 4;
    else if (orC) mode = 0;
    else mode = orD ? 1 : 2;
    for (int i = tid; i < 1200; i += 256) deo[i] = ldin(de, i, bf);
    if (tid < 24) abo[tid] = ldin(ab, tid, bf);
    const unsigned char* p = (const unsigned char*)mraw;
    for (int wI = tid; wI < n / 32; wI += 256) {
        unsigned word = 0;
        for (int j = 0; j < 32; ++j) {
            int i = wI * 32 + j;
            int v;
            switch (mode) {
                case 0: v = p[i]; break;
                case 1: v = ((const int*)p)[i]; break;
                case 2: v = (int)((const long long*)p)[i]; break;
                case 3: v = ((const u16*)p)[i] != 0; break;
                default: v = (((const float*)p)[i] != 0.0f); break;
            }
            if (v) word |= 1u << j;
        }
        mbits[wI] = word;
        smb[wI] = word;
    }
    __syncthreads();
    // --- kprep fold: 64-lane groups sweep batches ---
    int lane = tid & 63;
    for (int bb = tid >> 6; bb < 32; bb += 4) {
        int pos_base = 0;
        for (int w = 0; w < 8; ++w) {
            unsigned lo = smb[bb * 16 + 2 * w], hi = smb[bb * 16 + 2 * w + 1];
            unsigned long long word = ((unsigned long long)hi << 32) | lo;
            unsigned long long un = ~word;   // 1 = unmasked
            int bit = (int)((un >> lane) & 1ull);
            unsigned long long before = un & ((1ull << lane) - 1ull);
            int pos = pos_base + __popcll(before);
            if (bit) kidxg[bb * 512 + pos] = (u16)(w * 64 + lane);
            pos_base += __popcll(un);
        }
        int nk = pos_base;
        int nkp = (nk + 31) & ~31;
        if (nkp == 0) nkp = 32;
        int nt = nkp >> 5;
        for (int j = nk + lane; j < nkp; j += 64) kidxg[bb * 512 + j] = 0;
        if (lane == 0) {
            nkt[bb] = nt;
            for (int t = 0; t < 16; ++t) tmask[bb * 16 + t] = 0;
            int rem = nk & 31;
            if (rem) tmask[bb * 16 + nt - 1] = 0xFFFFFFFFu << rem;
            if (nk == 0) tmask[bb * 16] = 0xFFFFFFFFu;
        }
    }
}

// ---------- setup2: binsc + init + wtrans fused (range-switched grid) ------
// [0,2048): binsc. [2048,3072): init copy. [3072,3840): wtrans.
__global__ __launch_bounds__(256) void setup2_kernel(
    const void* __restrict__ dist, const u16* __restrict__ kidxg,
    const int* __restrict__ nktp, unsigned char* __restrict__ binsc,
    const void* x, float* __restrict__ h,
    const void* Wqr, const void* Wkr, const void* Wvr, const void* Wor,
    const void* Wf1r, const void* Wf2r,
    u16* qkvT, u16* oT, u16* f1T, u16* f2T, const int* flagp) {
    __shared__ u16 kl[512];
    __shared__ int ntS;
    __shared__ u16 Ts[32][33];
    int id = blockIdx.x;
    int tid = threadIdx.x;
    int bf = *flagp;
    if (id < 2048) {
        int b = id >> 6;
        int q0 = (id & 63) * 8;
        if (tid == 0) ntS = nktp[b];
        kl[tid] = kidxg[b * 512 + tid];
        kl[tid + 256] = kidxg[b * 512 + tid + 256];
        __syncthreads();
        int nkp = ntS * 32;
        for (int rq = 0; rq < 8; ++rq) {
            int q = q0 + rq;
            long rowoff = ((long)b * 512 + q) * 512;
            for (int j = tid; j < nkp; j += 256) {
                float d = ldin(dist, rowoff + kl[j], bf);
                int v = (int)(d * 10.0f);
                v = v < 0 ? 0 : (v > 49 ? 49 : v);
                binsc[((size_t)b * 512 + q) * 512 + j] = (unsigned char)(v << 2);
            }
        }
    } else if (id < 3072) {
        int i = (id - 2048) * 256 + tid;
        long base = (long)i * 8;
        if (bf) {
            uint4 w = ((const uint4*)x)[i];
            const u16* ws = (const u16*)&w;
            float o[8];
#pragma unroll
            for (int k = 0; k < 8; ++k) o[k] = bf2f(ws[k]);
            *(float4*)&h[base] = *(float4*)&o[0];
            *(float4*)&h[base + 4] = *(float4*)&o[4];
        } else {
            float4 a = ((const float4*)x)[2 * i];
            float4 b2v = ((const float4*)x)[2 * i + 1];
            *(float4*)&h[base] = a;
            *(float4*)&h[base + 4] = b2v;
        }
    } else {
        int bid = id - 3072;
        int l = bid >> 8, r = bid & 255;
        const void* src; u16* dst; long soff, doff; int Kd, Nd, t;
        if (r < 64) {
            int mat = r >> 4; t = r & 15; Kd = 128; Nd = 128;
            soff = (long)l * 16384;
            if (mat == 0)      { src = Wqr; dst = qkvT; doff = (long)l * 49152; }
            else if (mat == 1) { src = Wkr; dst = qkvT; doff = (long)l * 49152 + 16384; }
            else if (mat == 2) { src = Wvr; dst = qkvT; doff = (long)l * 49152 + 32768; }
            else               { src = Wor; dst = oT;   doff = (long)l * 16384; }
        } else if (r < 192) {
            t = r - 64; Kd = 128; Nd = 1024;
            src = Wf1r; soff = (long)l * 131072; dst = f1T; doff = (long)l * 131072;
        } else {
            t = r - 192; Kd = 512; Nd = 128;
            src = Wf2r; soff = (long)l * 65536; dst = f2T; doff = (long)l * 65536;
        }
        int ntile = Nd >> 5;
        int tk = t / ntile, tn = t % ntile;
        int rr = tid >> 3, cc0 = (tid & 7) * 4;
#pragma unroll
        for (int i = 0; i < 4; ++i) {
            long idx = soff + (long)(tk * 32 + rr) * Nd + tn * 32 + cc0 + i;
            Ts[rr][cc0 + i] = f2bf(ldin(src, idx, bf));
        }
        __syncthreads();
#pragma unroll
        for (int i = 0; i < 4; ++i) {
            long idx = doff + (long)(tn * 32 + rr) * Kd + tk * 32 + cc0 + i;
            dst[idx] = Ts[cc0 + i][rr];
        }
    }
}

// ===== QKV (layer 0 only): LN once, Q/K/V looped, B streamed from L2 =====
__global__ __launch_bounds__(256, 4) void qkv_mfma_kernel(
    const float* __restrict__ h, const u16* __restrict__ qkvT_l,
    const void* bqr, const void* bkr, const void* bvr, long bOff,
    const void* g1raw, const void* b1raw, long lnOff,
    u16* __restrict__ Qo, u16* __restrict__ Ko, u16* __restrict__ Vo,
    const int* flagp) {
    __shared__ __align__(16) u16 As[32][136];
    int tid = threadIdx.x;
    int m0 = blockIdx.x * 32;
    int bf = *flagp;
    {
        int row = tid >> 3, c0 = (tid & 7) * 16;
        const float* hp = h + (size_t)(m0 + row) * 128 + c0;
        float4 f0 = *(const float4*)(hp);
        float4 f1 = *(const float4*)(hp + 4);
        float4 f2 = *(const float4*)(hp + 8);
        float4 f3 = *(const float4*)(hp + 12);
        float vv[16] = {f0.x, f0.y, f0.z, f0.w, f1.x, f1.y, f1.z, f1.w,
                        f2.x, f2.y, f2.z, f2.w, f3.x, f3.y, f3.z, f3.w};
        float s = 0.f, s2 = 0.f;
#pragma unroll
        for (int k = 0; k < 16; ++k) { s += vv[k]; s2 += vv[k] * vv[k]; }
#pragma unroll
        for (int o = 1; o < 8; o <<= 1) {
            s += __shfl_xor(s, o);
            s2 += __shfl_xor(s2, o);
        }
        float mu = s * (1.0f / 128.0f);
        float var = fmaxf(s2 * (1.0f / 128.0f) - mu * mu, 0.0f);
        float rstd = rsqrtf(var + 1e-5f);
        u16 tmp[16];
#pragma unroll
        for (int k = 0; k < 16; ++k) {
            float g = ldin(g1raw, lnOff + c0 + k, bf);
            float b = ldin(b1raw, lnOff + c0 + k, bf);
            tmp[k] = f2bf((vv[k] - mu) * rstd * g + b);
        }
        *(uint4*)&As[row][c0]     = *(uint4*)&tmp[0];
        *(uint4*)&As[row][c0 + 8] = *(uint4*)&tmp[8];
    }
    __syncthreads();
    int wave = tid >> 6, lane = tid & 63;
    int q = lane >> 4, ln = lane & 15;
    int nb = wave * 32;
    f32x4 zero = {0.f, 0.f, 0.f, 0.f};
#pragma unroll
    for (int mat = 0; mat < 3; ++mat) {
        const u16* WT = qkvT_l + (size_t)mat * 16384;
        const void* braw = mat == 0 ? bqr : (mat == 1 ? bkr : bvr);
        u16* C = mat == 0 ? Qo : (mat == 1 ? Ko : Vo);
        float scale = mat == 0 ? QSCALE : 1.0f;
        short8 bfr[2][4];
#pragma unroll
        for (int t = 0; t < 2; ++t)
#pragma unroll
            for (int k4 = 0; k4 < 4; ++k4)
                bfr[t][k4] = *(const short8*)(WT + (size_t)(nb + t * 16 + ln) * 128
                                              + k4 * 32 + q * 8);
        f32x4 acc[2][2];
#pragma unroll
        for (int i = 0; i < 2; ++i)
#pragma unroll
            for (int j = 0; j < 2; ++j) acc[i][j] = zero;
#pragma unroll
        for (int k4 = 0; k4 < 4; ++k4) {
            short8 af0 = *(const short8*)&As[ln][k4 * 32 + q * 8];
            short8 af1 = *(const short8*)&As[16 + ln][k4 * 32 + q * 8];
#pragma unroll
            for (int t = 0; t < 2; ++t) {
                acc[0][t] = __builtin_amdgcn_mfma_f32_16x16x32_bf16(
                    af0, bfr[t][k4], acc[0][t], 0, 0, 0);
                acc[1][t] = __builtin_amdgcn_mfma_f32_16x16x32_bf16(
                    af1, bfr[t][k4], acc[1][t], 0, 0, 0);
            }
        }
#pragma unroll
        for (int t = 0; t < 2; ++t) {
            int n = nb + t * 16 + ln;
            float bias = ldin(braw, bOff + n, bf);
#pragma unroll
            for (int mi = 0; mi < 2; ++mi)
#pragma unroll
                for (int r = 0; r < 4; ++r) {
                    int m = m0 + mi * 16 + q * 4 + r;
                    C[(size_t)m * 128 + n] = f2h((acc[mi][t][r] + bias) * scale);
                }
        }
    }
}

// ===== fused FFN v8: round-13 pipelined structure + hoisted A-fragments ====
// (hn2 frags live in registers across ff1 chunks; As frags hoisted for qkv
// tail) + exp2-domain sigmoid. 32-row tiles, grid 512, 6 barriers.
__global__ __launch_bounds__(256, 3) void ffglu_kernel(
    const u16* __restrict__ att, const u16* __restrict__ oT_l,
    const void* __restrict__ bo, long boOff, float* __restrict__ h,
    const void* g2, const void* b2, long ln2Off,
    const u16* __restrict__ f1T_l, const void* __restrict__ bf1r, long bf1Off,
    const u16* __restrict__ f2T_l, const void* __restrict__ bf2r, long bf2Off,
    void* __restrict__ outp, const int* flagp,
    const u16* __restrict__ qkvTn,    // next layer qkvT (or nullptr)
    const void* bqr, const void* bkr, const void* bvr, long bOffN,
    const void* g1, const void* b1, long ln1OffN,
    u16* __restrict__ Qo, u16* __restrict__ Ko, u16* __restrict__ Vo) {
    __shared__ __align__(16) u16 As[32][136];   // att stage / hn2 / hn1-next
    __shared__ __align__(16) u16 vg[32][520];   // GLU output (never to HBM)
    __shared__ float stats[32][4][2];
    int tid = threadIdx.x;
    int m0 = blockIdx.x * 32;
    int wave = tid >> 6, lane = tid & 63;
    int q = lane >> 4, ln = lane & 15;
    int nb = wave * 32;
    int bf = *flagp;
    f32x4 zero = {0.f, 0.f, 0.f, 0.f};

    // ---- entry: issue h-residual loads + o-proj B loads + att staging ----
    float hres[2][2][4];
#pragma unroll
    for (int t = 0; t < 2; ++t)
#pragma unroll
        for (int mi = 0; mi < 2; ++mi)
#pragma unroll
            for (int r = 0; r < 4; ++r)
                hres[t][mi][r] = h[(size_t)(m0 + mi * 16 + q * 4 + r) * 128
                                   + nb + t * 16 + ln];
    short8 ob[2][4];
#pragma unroll
    for (int t = 0; t < 2; ++t)
#pragma unroll
        for (int k4 = 0; k4 < 4; ++k4)
            ob[t][k4] = *(const short8*)(oT_l + (size_t)(nb + t * 16 + ln) * 128
                                         + k4 * 32 + q * 8);
#pragma unroll
    for (int i = 0; i < 2; ++i) {
        int idx = tid + i * 256; int r = idx >> 4, c = (idx & 15) << 3;
        *(uint4*)&As[r][c] = *(const uint4*)(att + (size_t)(m0 + r) * 128 + c);
    }
    __syncthreads();                                   // B1
    // ---- o-proj MFMA ----
    f32x4 acc[2][2];
#pragma unroll
    for (int i = 0; i < 2; ++i)
#pragma unroll
        for (int j = 0; j < 2; ++j) acc[i][j] = zero;
#pragma unroll
    for (int k4 = 0; k4 < 4; ++k4) {
        short8 af0 = *(const short8*)&As[ln][k4 * 32 + q * 8];
        short8 af1 = *(const short8*)&As[16 + ln][k4 * 32 + q * 8];
#pragma unroll
        for (int t = 0; t < 2; ++t) {
            acc[0][t] = __builtin_amdgcn_mfma_f32_16x16x32_bf16(
                af0, ob[t][k4], acc[0][t], 0, 0, 0);
            acc[1][t] = __builtin_amdgcn_mfma_f32_16x16x32_bf16(
                af1, ob[t][k4], acc[1][t], 0, 0, 0);
        }
    }
    // ---- epilogue: +bias +resid(hres) -> h1 regs; LN2 partial stats ----
    float h1[2][2][4];
    float srow[2][4], s2row[2][4];
#pragma unroll
    for (int mi = 0; mi < 2; ++mi)
#pragma unroll
        for (int r = 0; r < 4; ++r) { srow[mi][r] = 0.f; s2row[mi][r] = 0.f; }
#pragma unroll
    for (int t = 0; t < 2; ++t) {
        int n = nb + t * 16 + ln;
        float bias = ldin(bo, boOff + n, bf);
#pragma unroll
        for (int mi = 0; mi < 2; ++mi)
#pragma unroll
            for (int r = 0; r < 4; ++r) {
                float v = acc[mi][t][r] + bias + hres[t][mi][r];
                h1[mi][t][r] = v;
                srow[mi][r] += v; s2row[mi][r] += v * v;
            }
    }
#pragma unroll
    for (int mi = 0; mi < 2; ++mi)
#pragma unroll
        for (int r = 0; r < 4; ++r)
#pragma unroll
            for (int o = 1; o < 16; o <<= 1) {
                srow[mi][r] += __shfl_xor(srow[mi][r], o);
                s2row[mi][r] += __shfl_xor(s2row[mi][r], o);
            }
    if (ln == 0) {
#pragma unroll
        for (int mi = 0; mi < 2; ++mi)
#pragma unroll
            for (int r = 0; r < 4; ++r) {
                stats[mi * 16 + q * 4 + r][wave][0] = srow[mi][r];
                stats[mi * 16 + q * 4 + r][wave][1] = s2row[mi][r];
            }
    }
    __syncthreads();                                   // B2
    // ---- LN2 -> hn2 (As overlay) ----
    float mu[2][4], rs[2][4];
#pragma unroll
    for (int mi = 0; mi < 2; ++mi)
#pragma unroll
        for (int r = 0; r < 4; ++r) {
            int row = mi * 16 + q * 4 + r;
            float s = (stats[row][0][0] + stats[row][1][0]) +
                      (stats[row][2][0] + stats[row][3][0]);
            float s2 = (stats[row][0][1] + stats[row][1][1]) +
                       (stats[row][2][1] + stats[row][3][1]);
            mu[mi][r] = s * (1.0f / 128.0f);
            float var = fmaxf(s2 * (1.0f / 128.0f) - mu[mi][r] * mu[mi][r], 0.0f);
            rs[mi][r] = rsqrtf(var + 1e-5f);
        }
#pragma unroll
    for (int t = 0; t < 2; ++t) {
        int n = nb + t * 16 + ln;
        float g = ldin(g2, ln2Off + n, bf), bb = ldin(b2, ln2Off + n, bf);
#pragma unroll
        for (int mi = 0; mi < 2; ++mi)
#pragma unroll
            for (int r = 0; r < 4; ++r)
                As[mi * 16 + q * 4 + r][n] =
                    f2bf((h1[mi][t][r] - mu[mi][r]) * rs[mi][r] * g + bb);
    }
    __syncthreads();                                   // B3
    // ---- hoist hn2 A-fragments to registers (used by all 8 ff1 chunks) ----
    short8 ha0[4], ha1[4];
#pragma unroll
    for (int k4 = 0; k4 < 4; ++k4) {
        ha0[k4] = *(const short8*)&As[ln][k4 * 32 + q * 8];
        ha1[k4] = *(const short8*)&As[16 + ln][k4 * 32 + q * 8];
    }
    // ---- ff1: 8 chunks of 64 GLU cols, pipelined weight loads ----
    int nb16 = wave * 16;
    short8 ba[4], bb8[4], ban[4], bbn[4];
#pragma unroll
    for (int k4 = 0; k4 < 4; ++k4) {
        ba[k4]  = *(const short8*)(f1T_l + (size_t)(nb16 + ln) * 128
                                   + k4 * 32 + q * 8);
        bb8[k4] = *(const short8*)(f1T_l + (size_t)(512 + nb16 + ln) * 128
                                   + k4 * 32 + q * 8);
    }
#pragma unroll
    for (int ch = 0; ch < 8; ++ch) {
        if (ch < 7) {
            int arow = (ch + 1) * 64 + nb16;
#pragma unroll
            for (int k4 = 0; k4 < 4; ++k4) {
                ban[k4] = *(const short8*)(f1T_l + (size_t)(arow + ln) * 128
                                           + k4 * 32 + q * 8);
                bbn[k4] = *(const short8*)(f1T_l + (size_t)(512 + arow + ln) * 128
                                           + k4 * 32 + q * 8);
            }
        }
        f32x4 aA[2] = {zero, zero}, aB[2] = {zero, zero};
#pragma unroll
        for (int k4 = 0; k4 < 4; ++k4) {
            aA[0] = __builtin_amdgcn_mfma_f32_16x16x32_bf16(ha0[k4], ba[k4], aA[0], 0, 0, 0);
            aA[1] = __builtin_amdgcn_mfma_f32_16x16x32_bf16(ha1[k4], ba[k4], aA[1], 0, 0, 0);
            aB[0] = __builtin_amdgcn_mfma_f32_16x16x32_bf16(ha0[k4], bb8[k4], aB[0], 0, 0, 0);
            aB[1] = __builtin_amdgcn_mfma_f32_16x16x32_bf16(ha1[k4], bb8[k4], aB[1], 0, 0, 0);
        }
        int n = ch * 64 + nb16 + ln;
        float bA = ldin(bf1r, bf1Off + n, bf);
        float bB = ldin(bf1r, bf1Off + 512 + n, bf);
#pragma unroll
        for (int mi = 0; mi < 2; ++mi)
#pragma unroll
            for (int r = 0; r < 4; ++r) {
                float ua = aA[mi][r] + bA, ub = aB[mi][r] + bB;
                float sig = 1.0f / (1.0f + __builtin_amdgcn_exp2f(-ub * LOG2E));
                vg[mi * 16 + q * 4 + r][n] = f2bf(ua * sig);
            }
        if (ch < 7) {
#pragma unroll
            for (int k4 = 0; k4 < 4; ++k4) { ba[k4] = ban[k4]; bb8[k4] = bbn[k4]; }
        }
    }
    __syncthreads();                                   // B4
    // ---- ff2: K=512 in 4 chunks, pipelined weight loads ----
    f32x4 accF[2][2];
#pragma unroll
    for (int i = 0; i < 2; ++i)
#pragma unroll
        for (int j = 0; j < 2; ++j) accF[i][j] = zero;
    short8 fb[2][4], fbn[2][4];
#pragma unroll
    for (int t = 0; t < 2; ++t)
#pragma unroll
        for (int k4 = 0; k4 < 4; ++k4)
            fb[t][k4] = *(const short8*)(f2T_l + (size_t)(nb + t * 16 + ln) * 512
                                         + k4 * 32 + q * 8);
#pragma unroll
    for (int fc = 0; fc < 4; ++fc) {
        if (fc < 3) {
            int k0 = (fc + 1) * 128;
#pragma unroll
            for (int t = 0; t < 2; ++t)
#pragma unroll
                for (int k4 = 0; k4 < 4; ++k4)
                    fbn[t][k4] = *(const short8*)(f2T_l
                                  + (size_t)(nb + t * 16 + ln) * 512
                                  + k0 + k4 * 32 + q * 8);
        }
#pragma unroll
        for (int k4 = 0; k4 < 4; ++k4) {
            short8 af0 = *(const short8*)&vg[ln][fc * 128 + k4 * 32 + q * 8];
            short8 af1 = *(const short8*)&vg[16 + ln][fc * 128 + k4 * 32 + q * 8];
#pragma unroll
            for (int t = 0; t < 2; ++t) {
                accF[0][t] = __builtin_amdgcn_mfma_f32_16x16x32_bf16(
                    af0, fb[t][k4], accF[0][t], 0, 0, 0);
                accF[1][t] = __builtin_amdgcn_mfma_f32_16x16x32_bf16(
                    af1, fb[t][k4], accF[1][t], 0, 0, 0);
            }
        }
        if (fc < 3) {
#pragma unroll
            for (int t = 0; t < 2; ++t)
#pragma unroll
                for (int k4 = 0; k4 < 4; ++k4) fb[t][k4] = fbn[t][k4];
        }
    }
    // ---- epilogue: +bias +resid -> h (and h1 regs for next-layer LN1) ----
#pragma unroll
    for (int t = 0; t < 2; ++t) {
        int n = nb + t * 16 + ln;
        float bias = ldin(bf2r, bf2Off + n, bf);
#pragma unroll
        for (int mi = 0; mi < 2; ++mi)
#pragma unroll
            for (int r = 0; r < 4; ++r) {
                int m = m0 + mi * 16 + q * 4 + r;
                float v = accF[mi][t][r] + bias + h1[mi][t][r];
                h[(size_t)m * 128 + n] = v;
                h1[mi][t][r] = v;   // reuse for LN1-next
                if (outp) {
                    if (bf) ((u16*)outp)[(size_t)m * 128 + n] = f2bf(v);
                    else ((float*)outp)[(size_t)m * 128 + n] = v;
                }
            }
    }
    if (!qkvTn) return;
    // ---- LN1 (next layer) stats ----
#pragma unroll
    for (int mi = 0; mi < 2; ++mi)
#pragma unroll
        for (int r = 0; r < 4; ++r) { srow[mi][r] = 0.f; s2row[mi][r] = 0.f; }
#pragma unroll
    for (int t = 0; t < 2; ++t)
#pragma unroll
        for (int mi = 0; mi < 2; ++mi)
#pragma unroll
            for (int r = 0; r < 4; ++r) {
                float v = h1[mi][t][r];
                srow[mi][r] += v; s2row[mi][r] += v * v;
            }
#pragma unroll
    for (int mi = 0; mi < 2; ++mi)
#pragma unroll
        for (int r = 0; r < 4; ++r)
#pragma unroll
            for (int o = 1; o < 16; o <<= 1) {
                srow[mi][r] += __shfl_xor(srow[mi][r], o);
                s2row[mi][r] += __shfl_xor(s2row[mi][r], o);
            }
    if (ln == 0) {
#pragma unroll
        for (int mi = 0; mi < 2; ++mi)
#pragma unroll
            for (int r = 0; r < 4; ++r) {
                stats[mi * 16 + q * 4 + r][wave][0] = srow[mi][r];
                stats[mi * 16 + q * 4 + r][wave][1] = s2row[mi][r];
            }
    }
    __syncthreads();                                   // B5
#pragma unroll
    for (int mi = 0; mi < 2; ++mi)
#pragma unroll
        for (int r = 0; r < 4; ++r) {
            int row = mi * 16 + q * 4 + r;
            float s = (stats[row][0][0] + stats[row][1][0]) +
                      (stats[row][2][0] + stats[row][3][0]);
            float s2 = (stats[row][0][1] + stats[row][1][1]) +
                       (stats[row][2][1] + stats[row][3][1]);
            mu[mi][r] = s * (1.0f / 128.0f);
            float var = fmaxf(s2 * (1.0f / 128.0f) - mu[mi][r] * mu[mi][r], 0.0f);
            rs[mi][r] = rsqrtf(var + 1e-5f);
        }
#pragma unroll
    for (int t = 0; t < 2; ++t) {
        int n = nb + t * 16 + ln;
        float g = ldin(g1, ln1OffN + n, bf), bb = ldin(b1, ln1OffN + n, bf);
#pragma unroll
        for (int mi = 0; mi < 2; ++mi)
#pragma unroll
            for (int r = 0; r < 4; ++r)
                As[mi * 16 + q * 4 + r][n] =
                    f2bf((h1[mi][t][r] - mu[mi][r]) * rs[mi][r] * g + bb);
    }
    __syncthreads();                                   // B6
    // ---- hoist hn1-next A-fragments (used by all 3 qkv mats) ----
#pragma unroll
    for (int k4 = 0; k4 < 4; ++k4) {
        ha0[k4] = *(const short8*)&As[ln][k4 * 32 + q * 8];
        ha1[k4] = *(const short8*)&As[16 + ln][k4 * 32 + q * 8];
    }
    // ---- next-layer QKV: B streamed, pipelined across mats ----
    short8 qb[2][4], qbn[2][4];
#pragma unroll
    for (int t = 0; t < 2; ++t)
#pragma unroll
        for (int k4 = 0; k4 < 4; ++k4)
            qb[t][k4] = *(const short8*)(qkvTn + (size_t)(nb + t * 16 + ln) * 128
                                         + k4 * 32 + q * 8);
#pragma unroll
    for (int mat = 0; mat < 3; ++mat) {
        if (mat < 2) {
            const u16* WTn = qkvTn + (size_t)(mat + 1) * 16384;
#pragma unroll
            for (int t = 0; t < 2; ++t)
#pragma unroll
                for (int k4 = 0; k4 < 4; ++k4)
                    qbn[t][k4] = *(const short8*)(WTn
                                  + (size_t)(nb + t * 16 + ln) * 128
                                  + k4 * 32 + q * 8);
        }
        const void* braw = mat == 0 ? bqr : (mat == 1 ? bkr : bvr);
        u16* C = mat == 0 ? Qo : (mat == 1 ? Ko : Vo);
        float scale = mat == 0 ? QSCALE : 1.0f;
        f32x4 aq[2][2];
#pragma unroll
        for (int i = 0; i < 2; ++i)
#pragma unroll
            for (int j = 0; j < 2; ++j) aq[i][j] = zero;
#pragma unroll
        for (int k4 = 0; k4 < 4; ++k4) {
#pragma unroll
            for (int t = 0; t < 2; ++t) {
                aq[0][t] = __builtin_amdgcn_mfma_f32_16x16x32_bf16(
                    ha0[k4], qb[t][k4], aq[0][t], 0, 0, 0);
                aq[1][t] = __builtin_amdgcn_mfma_f32_16x16x32_bf16(
                    ha1[k4], qb[t][k4], aq[1][t], 0, 0, 0);
            }
        }
#pragma unroll
        for (int t = 0; t < 2; ++t) {
            int n = nb + t * 16 + ln;
            float bias = ldin(braw, bOffN + n, bf);
#pragma unroll
            for (int mi = 0; mi < 2; ++mi)
#pragma unroll
                for (int r = 0; r < 4; ++r) {
                    int m = m0 + mi * 16 + q * 4 + r;
                    C[(size_t)m * 128 + n] = f2h((aq[mi][t][r] + bias) * scale);
                }
        }
        if (mat < 2) {
#pragma unroll
            for (int t = 0; t < 2; ++t)
#pragma unroll
                for (int k4 = 0; k4 < 4; ++k4) qb[t][k4] = qbn[t][k4];
        }
    }
}

// ========== attention v6: exp2-domain softmax (Q pre-scaled by log2e) =======
__global__ __launch_bounds__(256, 4) void attn_kernel(
    const u16* __restrict__ Qh, const u16* __restrict__ Kh,
    const u16* __restrict__ Vh, const unsigned char* __restrict__ binsc,
    const u16* __restrict__ kidxg, const int* __restrict__ nktp,
    const unsigned* __restrict__ tmaskp, const float* __restrict__ deL,
    const float* __restrict__ abL, u16* __restrict__ out) {
    // de-swizzle: heads of one (b,qq) share id%8 -> same XCD L2 for binsc
    int id = blockIdx.x;
    int c = id & 7, t5 = id >> 3;
    int nh = t5 & 7;
    int pair = ((t5 >> 3) << 3) | c;
    int b = pair >> 2, qq = pair & 3;

    __shared__ __align__(16) u16 KsF[8192];      // frag-major K, 16 KB
    __shared__ __align__(16) u16 VT[16 * 520];   // V^T rows 520 f16, 16.25 KB
    __shared__ __align__(16) u16 Pl[4 * 16 * 40];// per-wave P tile, 5 KB

    int tid = threadIdx.x;
    int nt = __builtin_amdgcn_readfirstlane(nktp[b]);
    int nkp = nt * 32;
    const u16* Kp = Kh + (size_t)(b * Nq) * Hq + nh * HDq;
    const u16* Vp = Vh + (size_t)(b * Nq) * Hq + nh * HDq;
    for (int r = tid; r < nkp; r += 256) {
        int row = kidxg[b * 512 + r];
        int kt = r >> 5, s = (r >> 4) & 1, lnr = r & 15;
        uint4 k0v = *(const uint4*)(Kp + (size_t)row * Hq);
        uint4 k1v = *(const uint4*)(Kp + (size_t)row * Hq + 8);
        *(uint4*)&KsF[kt * 512 + s * 256 + lnr * 8]       = k0v;  // d 0..7
        *(uint4*)&KsF[kt * 512 + s * 256 + 128 + lnr * 8] = k1v;  // d 8..15
        uint4 v0 = *(const uint4*)(Vp + (size_t)row * Hq);
        uint4 v1 = *(const uint4*)(Vp + (size_t)row * Hq + 8);
        u16 vv[16];
        *(uint4*)&vv[0] = v0; *(uint4*)&vv[8] = v1;
#pragma unroll
        for (int d = 0; d < 16; ++d) VT[d * 520 + r] = vv[d];
    }
    __syncthreads();

    int wave = tid >> 6, lane = tid & 63;
    int quad = lane >> 4, ln = lane & 15;
    int q0w = qq * 128 + wave * 32;

    float tblf = (lane < 50) ? (deL[lane * NHq + nh] + abL[nh]) * LOG2E : 0.0f;
    int tbli = __float_as_int(tblf);
    unsigned tl = tmaskp[b * 16 + nt - 1];

    // hoisted Q B-frags (quads 2,3 supply the zero d-padding)
    half8 qf[2];
#pragma unroll
    for (int t = 0; t < 2; ++t) {
        uint4 qv = {0, 0, 0, 0};
        if (quad < 2)
            qv = *(const uint4*)(Qh + (size_t)(b * Nq + q0w + t * 16 + ln) * Hq
                                 + nh * HDq + quad * 8);
        qf[t] = *(half8*)&qv;
    }

    f32x4 zero = {0.f, 0.f, 0.f, 0.f};
    f32x4 acc[2] = {zero, zero};
    float zp[2] = {0.f, 0.f};
    _Float16* Pw = (_Float16*)&Pl[wave * 640];
    const _Float16* KsH = (const _Float16*)KsF;
    const _Float16* VTH = (const _Float16*)VT;
    const unsigned char* brow0 = binsc + ((size_t)b * 512 + (q0w + ln)) * 512;
    const unsigned char* brow1 = brow0 + (size_t)16 * 512;

    // prefetch kt=0 bias-byte dwords
    unsigned pb00 = *(const unsigned*)(brow0 + quad * 4);
    unsigned pb01 = *(const unsigned*)(brow0 + 16 + quad * 4);
    unsigned pb10 = *(const unsigned*)(brow1 + quad * 4);
    unsigned pb11 = *(const unsigned*)(brow1 + 16 + quad * 4);

    for (int kt = 0; kt < nt; ++kt) {
        int k0 = kt * 32;
        unsigned w = (kt == nt - 1) ? tl : 0u;
        unsigned cb00 = pb00, cb01 = pb01, cb10 = pb10, cb11 = pb11;
        if (kt < nt - 1) {
            pb00 = *(const unsigned*)(brow0 + k0 + 32 + quad * 4);
            pb01 = *(const unsigned*)(brow0 + k0 + 48 + quad * 4);
            pb10 = *(const unsigned*)(brow1 + k0 + 32 + quad * 4);
            pb11 = *(const unsigned*)(brow1 + k0 + 48 + quad * 4);
        }
        half8 vb = *(const half8*)(VTH + ln * 520 + k0 + quad * 8);
        half8 ka0 = {}, ka1 = {};
        if (quad < 2) {
            ka0 = *(const half8*)(KsH + kt * 512 + quad * 128 + ln * 8);
            ka1 = *(const half8*)(KsH + kt * 512 + 256 + quad * 128 + ln * 8);
        }
#pragma unroll
        for (int t = 0; t < 2; ++t) {
            unsigned bw0 = t == 0 ? cb00 : cb10;
            unsigned bw1 = t == 0 ? cb01 : cb11;
            f32x4 s0 = __builtin_amdgcn_mfma_f32_16x16x32_f16(ka0, qf[t], zero, 0, 0, 0);
            f32x4 s1 = __builtin_amdgcn_mfma_f32_16x16x32_f16(ka1, qf[t], zero, 0, 0, 0);
            float p[8];
#pragma unroll
            for (int r = 0; r < 4; ++r) {
                float bias = __int_as_float(__builtin_amdgcn_ds_bpermute(
                    (int)((bw0 >> (8 * r)) & 0xFFu), tbli));
                float sc = s0[r] + bias;
                bool m = (w >> (quad * 4 + r)) & 1u;
                p[r] = m ? 0.0f : __builtin_amdgcn_exp2f(sc);
            }
#pragma unroll
            for (int r = 0; r < 4; ++r) {
                float bias = __int_as_float(__builtin_amdgcn_ds_bpermute(
                    (int)((bw1 >> (8 * r)) & 0xFFu), tbli));
                float sc = s1[r] + bias;
                bool m = (w >> (16 + quad * 4 + r)) & 1u;
                p[4 + r] = m ? 0.0f : __builtin_amdgcn_exp2f(sc);
            }
            zp[t] += ((p[0] + p[1]) + (p[2] + p[3])) +
                     ((p[4] + p[5]) + (p[6] + p[7]));
            uint2 w0, w1;
            w0.x = pk2h(p[0], p[1]); w0.y = pk2h(p[2], p[3]);
            w1.x = pk2h(p[4], p[5]); w1.y = pk2h(p[6], p[7]);
            *(uint2*)(Pw + ln * 40 + quad * 4)      = w0;   // k = quad*4+r
            *(uint2*)(Pw + ln * 40 + 16 + quad * 4) = w1;   // k = 16+quad*4+r
            half8 pa = *(const half8*)(Pw + ln * 40 + quad * 8); // A[m=ln][k=quad*8+j]
            acc[t] = __builtin_amdgcn_mfma_f32_16x16x32_f16(pa, vb, acc[t], 0, 0, 0);
        }
    }
#pragma unroll
    for (int t = 0; t < 2; ++t) {
        zp[t] += __shfl_xor(zp[t], 16);
        zp[t] += __shfl_xor(zp[t], 32);
    }
#pragma unroll
    for (int t = 0; t < 2; ++t) {
#pragma unroll
        for (int r = 0; r < 4; ++r) {
            float zz = __shfl(zp[t], quad * 4 + r);
            float val = acc[t][r] / fmaxf(zz, 1e-35f);
            int qrow = q0w + t * 16 + quad * 4 + r;
            out[(size_t)(b * Nq + qrow) * Hq + nh * HDq + ln] = f2bf(val);
        }
    }
}

extern "C" void kernel_launch(void* const* d_in, const int* in_sizes, int n_in,
                              void* d_out, int out_size, void* d_ws, size_t ws_size,
                              hipStream_t stream) {
    const void* x  = d_in[0];
    const void* dist = d_in[1];
    const void* mask = d_in[2];
    const void* Wq = d_in[3];  const void* bq = d_in[4];
    const void* Wk = d_in[5];  const void* bk = d_in[6];
    const void* Wv = d_in[7];  const void* bv = d_in[8];
    const void* Wo = d_in[9];  const void* bo = d_in[10];
    const void* de = d_in[11]; const void* ab = d_in[12];
    const void* g1 = d_in[13]; const void* b1 = d_in[14];
    const void* g2 = d_in[15]; const void* b2 = d_in[16];
    const void* Wf1 = d_in[17]; const void* bf1 = d_in[18];
    const void* Wf2 = d_in[19]; const void* bf2 = d_in[20];

    char* ws = (char*)d_ws;
    const size_t OFF_DE   = 64;
    const size_t OFF_AB   = 5120;
    const size_t OFF_BINS = 8192;                    // binsc 8,388,608
    const size_t OFF_MSK  = OFF_BINS + 8388608;      // mbits 2 KB (4096 res)
    const size_t OFF_KIDX = OFF_MSK + 4096;          // 32768
    const size_t OFF_NKT  = OFF_KIDX + 32768;        // 256
    const size_t OFF_TM   = OFF_NKT + 256;           // 2048
    const size_t OFF_H    = OFF_TM + 4096;           // f32 8,388,608
    const size_t OFF_QKV  = OFF_H + 8388608;         // Qh,Kh,Vh f16
    const size_t OFF_ATT  = OFF_QKV + 25165824;      // u16 4,194,304
    const size_t OFF_WT   = OFF_ATT + 4194304;       // u16 1,572,864
    const size_t NEEDED   = OFF_WT + 1572864;
    if (ws_size < NEEDED) return;

    int* flag = (int*)ws;
    float* deF = (float*)(ws + OFF_DE);
    float* abF = (float*)(ws + OFF_AB);
    unsigned char* binsc = (unsigned char*)(ws + OFF_BINS);
    unsigned* mbits = (unsigned*)(ws + OFF_MSK);
    u16* kidxg = (u16*)(ws + OFF_KIDX);
    int* nkt = (int*)(ws + OFF_NKT);
    unsigned* tmask = (unsigned*)(ws + OFF_TM);
    float* h = (float*)(ws + OFF_H);
    u16* Qh = (u16*)(ws + OFF_QKV);
    u16* Kh = Qh + 2097152;
    u16* Vh = Qh + 2 * 2097152;
    u16* att = (u16*)(ws + OFF_ATT);
    u16* qkvT = (u16*)(ws + OFF_WT);
    u16* oT  = qkvT + 147456;
    u16* f1T = oT + 49152;
    u16* f2T = f1T + 393216;

    prep_kernel<<<1, 256, 0, stream>>>(x, de, ab, mask, flag, deF, abF, mbits,
                                       Bq * Nq, kidxg, nkt, tmask);
    setup2_kernel<<<3840, 256, 0, stream>>>(dist, kidxg, nkt, binsc, x, h,
                                            Wq, Wk, Wv, Wo, Wf1, Wf2,
                                            qkvT, oT, f1T, f2T, flag);
    qkv_mfma_kernel<<<512, 256, 0, stream>>>(h, qkvT, bq, bk, bv, 0,
                                             g1, b1, 0, Qh, Kh, Vh, flag);
    for (int l = 0; l < 3; ++l) {
        attn_kernel<<<1024, 256, 0, stream>>>(Qh, Kh, Vh, binsc, kidxg, nkt, tmask,
                                              deF + (long)l * 400, abF + (long)l * 8, att);
        ffglu_kernel<<<512, 256, 0, stream>>>(
            att, oT + (size_t)l * 16384, bo, (long)l * Hq,
            h, g2, b2, (long)l * Hq,
            f1T + (size_t)l * 131072, bf1, (long)l * 1024,
            f2T + (size_t)l * 65536, bf2, (long)l * Hq,
            l == 2 ? d_out : nullptr, flag,
            l < 2 ? qkvT + (size_t)(l + 1) * 49152 : (const u16*)nullptr,
            bq, bk, bv, (long)(l + 1) * Hq,
            g1, b1, (long)(l + 1) * Hq,
            Qh, Kh, Vh);
    }
}